// Round 1
// 175.959 us; speedup vs baseline: 1.0443x; 1.0443x over previous
//
#include <hip/hip_runtime.h>

// ---------------------------------------------------------------------------
// Multihead self-attention with RoPE, MI355X (gfx950).  Round 10.
// B=2, S=2048, H=16, DH=64, DM=1024.
// R10: counted-vmcnt staging pipeline (T4) in gemm_core. Diagnosis from R9
// counters: qkv_gemm 67us = 1675 cyc/block-iter vs 740 for the identical
// m97-structure steady state; MFMA pipe 19%, LDS pipe 23%, HBM 4.7% -> the
// loop is stall-bound on the vmcnt(0) drain before each __syncthreads().
// Staging working set (~7-8 MB/XCD: X panels + Wq+Wk+Wv) thrashes the 4 MB
// L2, so global_load_lds latency (~600-900 cyc L3/HBM) > 1 loop body
// (~700 cyc) and is exposed at every barrier. Fix: 3 LDS buffers, prefetch
// 2 K-tiles ahead, s_waitcnt vmcnt(NLD) (never 0 in steady state) + raw
// s_barrier -> latency budget ~2 loop bodies. LDS 32->48 KB (qkv) keeps
// 3 blocks/CU (144<=160); __launch_bounds__(256,3) pins regalloc.
// flash_attn / cast_all untouched for clean attribution.
// ---------------------------------------------------------------------------

typedef __attribute__((ext_vector_type(8))) short bf16x8;
typedef __attribute__((ext_vector_type(4))) float f32x4;

__device__ __forceinline__ short f2bf(float f) {
  unsigned u = __float_as_uint(f);
  unsigned r = (u + 0x7fffu + ((u >> 16) & 1u)) >> 16;   // RNE
  return (short)(r & 0xFFFFu);
}

// pack two f32 -> adjacent bf16 (round-half-up via +0x8000), one v_perm_b32
__device__ __forceinline__ unsigned pk2(float a, float b) {
  return __builtin_amdgcn_perm(__float_as_uint(b) + 0x8000u,
                               __float_as_uint(a) + 0x8000u, 0x07060302u);
}

// async global->LDS, 16B per lane. LDS dest must be wave-uniform base + lane*16.
__device__ __forceinline__ void async16(const void* g, void* l) {
  __builtin_amdgcn_global_load_lds(
      (const __attribute__((address_space(1))) void*)g,
      (__attribute__((address_space(3))) void*)l, 16, 0, 0);
}

__device__ __forceinline__ void cstore(short* C, size_t i, float v) { C[i] = f2bf(v); }
__device__ __forceinline__ void cstore(float* C, size_t i, float v) { C[i] = v; }

// ---------------------------------------------------------------------------
// merged f32 -> bf16 cast: X (1M float4) then Wq|Wk|Wv|Wo (dsts contiguous).
// ---------------------------------------------------------------------------
__global__ void cast_all(const float4* __restrict__ X,
                         const float4* __restrict__ w0, const float4* __restrict__ w1,
                         const float4* __restrict__ w2, const float4* __restrict__ w3,
                         short* __restrict__ Xb, short* __restrict__ Wb) {
  int t = blockIdx.x * 256 + threadIdx.x;
  const float4* s;
  short4* d;
  if (t < (1 << 20)) {
    s = X + t; d = (short4*)Xb + t;
  } else {
    int u = t - (1 << 20);
    int which = u >> 18;
    s = ((which == 0) ? w0 : (which == 1) ? w1 : (which == 2) ? w2 : w3) + (u & 0x3FFFF);
    d = (short4*)Wb + u;
  }
  float4 v = *s;
  *d = make_short4(f2bf(v.x), f2bf(v.y), f2bf(v.z), f2bf(v.w));
}

// ---------------------------------------------------------------------------
// bf16 GEMM core: C[M,N] = A[M,K] * B[N,K]^T, K=1024, lda=ldb=1024.
// BM=32*MR, BN=32*NR; 4 waves 2x2. LDS passed in (3 buffers each for A,B).
// R10: 3-deep ring, prefetch 2 K-tiles ahead, counted vmcnt + raw s_barrier.
// Epilogue modes: EPI_ROW row-major; EPI_KFRAG / EPI_VFRAG fragment-major
// (per (b,h,kt,nb,half): 512-short segment in exact MFMA lane order).
// ---------------------------------------------------------------------------
enum EpiMode { EPI_ROW, EPI_KFRAG, EPI_VFRAG };

template <typename OUT, int MR, int NR, bool ROPE, EpiMode EM>
__device__ __forceinline__ void gemm_core(short* __restrict__ As, short* __restrict__ Bs,
                                          const short* __restrict__ A, const short* __restrict__ B,
                                          OUT* __restrict__ C, int bm, int bn, int ldc,
                                          const int* __restrict__ pos) {
  constexpr int BM = 32 * MR, BN = 32 * NR;
  constexpr int NLD = (BM * 4 + BN * 4) / 256;   // global_load_lds per wave per stage
  const int tid  = threadIdx.x;
  const int lane = tid & 63, wave = tid >> 6;
  const int col  = lane & 15, quad = lane >> 4;
  const int wm = (wave & 1) * (16 * MR), wn = (wave >> 1) * (16 * NR);

  f32x4 acc[MR][NR];
#pragma unroll
  for (int i = 0; i < MR; i++)
#pragma unroll
    for (int j = 0; j < NR; j++) acc[i][j] = (f32x4){0.f, 0.f, 0.f, 0.f};

  auto stage = [&](int k0, int bu) {
#pragma unroll
    for (int c = tid; c < BM * 4; c += 256) {
      int r = c >> 2, cc = (c & 3) << 3;
      async16(A + (size_t)(bm + r) * 1024 + k0 + cc, As + bu * BM * 32 + c * 8);
    }
#pragma unroll
    for (int c = tid; c < BN * 4; c += 256) {
      int r = c >> 2, cc = (c & 3) << 3;
      async16(B + (size_t)(bn + r) * 1024 + k0 + cc, Bs + bu * BN * 32 + c * 8);
    }
  };

  // prologue: 2 stages in flight, wait for stage 0 only (vmcnt leaves NLD).
  stage(0, 0);
  stage(32, 1);
  if constexpr (NLD == 4) asm volatile("s_waitcnt vmcnt(4)" ::: "memory");
  else                    asm volatile("s_waitcnt vmcnt(3)" ::: "memory");
  __builtin_amdgcn_s_barrier();

  int cur = 0, nxt = 2;
  for (int it = 0; it < 32; ++it) {
    if (it < 30) stage((it + 2) * 32, nxt);
    const short* as = As + cur * (BM * 32);
    const short* bs = Bs + cur * (BN * 32);

    bf16x8 af[MR], bfr[NR];
#pragma unroll
    for (int i = 0; i < MR; i++)
      af[i] = *(const bf16x8*)(as + (wm + i * 16 + col) * 32 + quad * 8);
#pragma unroll
    for (int i = 0; i < NR; i++)
      bfr[i] = *(const bf16x8*)(bs + (wn + i * 16 + col) * 32 + quad * 8);
#pragma unroll
    for (int mi = 0; mi < MR; mi++)
#pragma unroll
      for (int ni = 0; ni < NR; ni++)
        acc[mi][ni] = __builtin_amdgcn_mfma_f32_16x16x32_bf16(af[mi], bfr[ni], acc[mi][ni], 0, 0, 0);

    // counted drain: oldest stage (it+1) must have landed; newest (it+2) may fly.
    if (it < 30) {
      if constexpr (NLD == 4) asm volatile("s_waitcnt vmcnt(4)" ::: "memory");
      else                    asm volatile("s_waitcnt vmcnt(3)" ::: "memory");
    } else {
      asm volatile("s_waitcnt vmcnt(0)" ::: "memory");
    }
    __builtin_amdgcn_s_barrier();
    cur = (cur == 2) ? 0 : cur + 1;
    nxt = (nxt == 2) ? 0 : nxt + 1;
  }

  if (ROPE) {
    float invf_rev[NR];
#pragma unroll
    for (int ni = 0; ni < NR; ni++) {
      int pr = ((bn + wn + ni * 16 + col) & 63) >> 1;
      invf_rev[ni] = exp2f(-0.4152410118609203f * (float)pr) * 0.15915494309189535f;
    }
    const float sgn = (col & 1) ? 1.f : -1.f;
#pragma unroll
    for (int mi = 0; mi < MR; mi++) {
#pragma unroll
      for (int r = 0; r < 4; r++) {
        int row = bm + wm + mi * 16 + quad * 4 + r;
        float fp = (float)pos[row & 2047];
#pragma unroll
        for (int ni = 0; ni < NR; ni++) {
          float rev = fp * invf_rev[ni];
          rev -= floorf(rev);
          float sn = __builtin_amdgcn_sinf(rev);
          float cs = __builtin_amdgcn_cosf(rev);
          float x  = acc[mi][ni][r];
          float px = __shfl_xor(x, 1);
          acc[mi][ni][r] = fmaf(x, cs, sgn * px * sn);
        }
      }
    }
  }

  if (EM == EPI_ROW) {
#pragma unroll
    for (int mi = 0; mi < MR; mi++) {
#pragma unroll
      for (int r = 0; r < 4; r++) {
        size_t row = (size_t)(bm + wm + mi * 16 + quad * 4 + r);
#pragma unroll
        for (int ni = 0; ni < NR; ni++) {
          int cg = bn + wn + ni * 16 + col;
          cstore(C, row * ldc + cg, acc[mi][ni][r]);
        }
      }
    }
  } else if (EM == EPI_KFRAG) {
    // rows m = tokens, cols e = embed
#pragma unroll
    for (int mi = 0; mi < MR; mi++) {
#pragma unroll
      for (int r = 0; r < 4; r++) {
        int m = bm + wm + mi * 16 + quad * 4 + r;
        int bq = m >> 11, key = m & 2047;
        int kt = key >> 6, nb = (key >> 4) & 3, cl = key & 15;
#pragma unroll
        for (int ni = 0; ni < NR; ni++) {
          int e = bn + wn + ni * 16 + col;
          int h = e >> 6, d = e & 63;
          size_t seg = ((((size_t)(bq * 16 + h) * 32 + kt) * 4 + nb) * 2 + (d >> 5));
          cstore((short*)C, seg * 512 + (((d >> 3) & 3) * 16 + cl) * 8 + (d & 7), acc[mi][ni][r]);
        }
      }
    }
  } else {   // EPI_VFRAG: rows e = embed, cols m = tokens
#pragma unroll
    for (int mi = 0; mi < MR; mi++) {
#pragma unroll
      for (int r = 0; r < 4; r++) {
        int e = bm + wm + mi * 16 + quad * 4 + r;
        int h = e >> 6, d = e & 63;
        int nb = d >> 4, cl = d & 15;
#pragma unroll
        for (int ni = 0; ni < NR; ni++) {
          int m = bn + wn + ni * 16 + col;
          int bq = m >> 11, key = m & 2047;
          int kt = key >> 6, k64 = key & 63;
          size_t seg = ((((size_t)(bq * 16 + h) * 32 + kt) * 4 + nb) * 2 + (k64 >> 5));
          cstore((short*)C, seg * 512 + (((k64 >> 3) & 3) * 16 + cl) * 8 + (k64 & 7), acc[mi][ni][r]);
        }
      }
    }
  }
}

// z=0: Q = rope(X Wq^T) row-major; z=1: Kf = rope(X Wk^T) frag-major;
// z=2: Vf = Wv X^T frag-major.
__global__ __launch_bounds__(256, 3) void qkv_gemm(const short* __restrict__ Xb,
                                                   const short* __restrict__ Wq,
                                                   const short* __restrict__ Wk,
                                                   const short* __restrict__ Wv,
                                                   short* __restrict__ Qo,
                                                   short* __restrict__ Kf,
                                                   short* __restrict__ Vf,
                                                   const int* __restrict__ pos) {
  __shared__ __align__(16) short sm[3 * 128 * 32 + 3 * 128 * 32];   // 48 KB shared
  short* As = sm;
  short* Bs = sm + 3 * 128 * 32;
  const int z = blockIdx.z;
  if (z == 0)      gemm_core<short, 4, 4, true,  EPI_ROW  >(As, Bs, Xb, Wq, Qo, blockIdx.x * 128, blockIdx.y * 128, 1024, pos);
  else if (z == 1) gemm_core<short, 4, 4, true,  EPI_KFRAG>(As, Bs, Xb, Wk, Kf, blockIdx.x * 128, blockIdx.y * 128, 0, pos);
  else             gemm_core<short, 4, 4, false, EPI_VFRAG>(As, Bs, Wv, Xb, Vf, blockIdx.y * 128, blockIdx.x * 128, 0, pos);
}

__global__ __launch_bounds__(256) void out_gemm(const short* __restrict__ Ctx,
                                                const short* __restrict__ Wo,
                                                float* __restrict__ C) {
  __shared__ __align__(16) short sm[3 * 64 * 32 + 3 * 128 * 32];    // 36 KB
  gemm_core<float, 2, 4, false, EPI_ROW>(sm, sm + 3 * 64 * 32, Ctx, Wo, C,
                                         blockIdx.x * 64, blockIdx.y * 128, 1024, nullptr);
}

// ---------------------------------------------------------------------------
// Flash attention, causal. grid (bh=32, pair=16), 256 threads = 4 INDEPENDENT
// waves (no __syncthreads). Block (bh,p) covers qt_a=p and qt_b=31-p; each
// wave runs its 16-row strip of qt_a then qt_b -> UNIFORM 33 ktiles/wave
// grid-wide (no makespan imbalance). Fragment-major K/V; register pipeline
// (vf at top, kf prefetched). Ps: stride-72 rows with XOR'd key chunks
// (nb ^ (col&3)) -> b64 writes 2-way max (free), reads 16B-aligned.
// ---------------------------------------------------------------------------
__global__ __launch_bounds__(256, 2) void flash_attn(const short* __restrict__ Q,
                                                     const short* __restrict__ Kf,
                                                     const short* __restrict__ Vf,
                                                     short* __restrict__ ctx) {
  const int p = blockIdx.y;
  const int bh = blockIdx.x;
  const int b = bh >> 4, h = bh & 15;
  __shared__ __align__(16) short Ps[4][16 * 72];         // per-wave P [q][key-chunk^]
  const int tid = threadIdx.x, lane = tid & 63, wave = tid >> 6;
  const int col = lane & 15, quad = lane >> 4;

  // fragment-major bases: bh covers 32 kt * 8 segs * 512 shorts = 131072
  const short* Kfb = Kf + (size_t)bh * 131072 + lane * 8;
  const short* Vfb = Vf + (size_t)bh * 131072 + lane * 8;

  const float C1 = 0.18033688011112042f;   // 0.125 * log2(e)
  const float C2 = 17.31234049066756f;     // 12 * log2(e)

  short* myPs = &Ps[wave][0];
  const int cx = col & 3;
  // write offsets per nb (xor-swizzled chunk), read offsets for af0/af1
  const int pswr0 = col * 72 + ((0 ^ cx) << 4) + quad * 4;
  const int pswr1 = col * 72 + ((1 ^ cx) << 4) + quad * 4;
  const int pswr2 = col * 72 + ((2 ^ cx) << 4) + quad * 4;
  const int pswr3 = col * 72 + ((3 ^ cx) << 4) + quad * 4;
  const int psrd0 = col * 72 + (((quad >> 1) ^ cx) << 4) + (quad & 1) * 8;
  const int psrd1 = col * 72 + ((((quad >> 1) + 2) ^ cx) << 4) + (quad & 1) * 8;

  auto ldk = [&](int kt, bf16x8 (&kf)[4][2]) {
    const int base = kt * 4096;
#pragma unroll
    for (int nb = 0; nb < 4; nb++) {
      kf[nb][0] = *(const bf16x8*)(Kfb + base + (nb * 2 + 0) * 512);
      kf[nb][1] = *(const bf16x8*)(Kfb + base + (nb * 2 + 1) * 512);
    }
  };
  auto ldv = [&](int kt, bf16x8 (&vf)[4][2]) {
    const int base = kt * 4096;
#pragma unroll
    for (int nb = 0; nb < 4; nb++) {
      vf[nb][0] = *(const bf16x8*)(Vfb + base + (nb * 2 + 0) * 512);
      vf[nb][1] = *(const bf16x8*)(Vfb + base + (nb * 2 + 1) * 512);
    }
  };

  auto process = [&](int qt) {
    // Q fragments (B-operand), one-time row-major gather
    const size_t qrow = (size_t)(b * 2048 + qt * 64 + wave * 16 + col);
    bf16x8 qf0 = *(const bf16x8*)(Q + qrow * 1024 + h * 64 + quad * 8);
    bf16x8 qf1 = *(const bf16x8*)(Q + qrow * 1024 + h * 64 + 32 + quad * 8);

    float l_i = 0.f;                                     // one q per lane (q=col)
    f32x4 o_acc[4];
#pragma unroll
    for (int i = 0; i < 4; i++) o_acc[i] = (f32x4){0.f, 0.f, 0.f, 0.f};

    const int qg = qt * 64 + wave * 16 + col;
    bf16x8 kf[4][2], vf[4][2];
    ldk(0, kf);

    for (int kt = 0; kt <= qt; ++kt) {
      // V for this tile: issued now, consumed at PV
      ldv(kt, vf);
      // S^T = K Q^T (kf prefetched last iteration)
      f32x4 s_acc[4];
#pragma unroll
      for (int nb = 0; nb < 4; nb++) {
        f32x4 z = (f32x4){0.f, 0.f, 0.f, 0.f};
        z = __builtin_amdgcn_mfma_f32_16x16x32_bf16(kf[nb][0], qf0, z, 0, 0, 0);
        z = __builtin_amdgcn_mfma_f32_16x16x32_bf16(kf[nb][1], qf1, z, 0, 0, 0);
        s_acc[nb] = z;
      }
      // prefetch next K
      if (kt < qt) ldk(kt + 1, kf);
      // softmax (fixed shift 12) + pack + b64 write (xor-swizzled chunk)
      const bool diag = (kt == qt);
#pragma unroll
      for (int nb = 0; nb < 4; nb++) {
        float pv[4];
#pragma unroll
        for (int r = 0; r < 4; r++) {
          pv[r] = exp2f(s_acc[nb][r] * C1 - C2);
          if (diag && (kt * 64 + nb * 16 + quad * 4 + r) > qg) pv[r] = 0.f;
          l_i += pv[r];
        }
        int wr = (nb == 0) ? pswr0 : (nb == 1) ? pswr1 : (nb == 2) ? pswr2 : pswr3;
        *(uint2*)(myPs + wr) = make_uint2(pk2(pv[0], pv[1]), pk2(pv[2], pv[3]));
      }
      // P fragment (A-op)
      bf16x8 af0 = *(const bf16x8*)(myPs + psrd0);
      bf16x8 af1 = *(const bf16x8*)(myPs + psrd1);
      // O += P V
#pragma unroll
      for (int nb = 0; nb < 4; nb++) {
        o_acc[nb] = __builtin_amdgcn_mfma_f32_16x16x32_bf16(af0, vf[nb][0], o_acc[nb], 0, 0, 0);
        o_acc[nb] = __builtin_amdgcn_mfma_f32_16x16x32_bf16(af1, vf[nb][1], o_acc[nb], 0, 0, 0);
      }
    }

    // l reduction over the 4 quads sharing this col
    l_i += __shfl_xor(l_i, 16);
    l_i += __shfl_xor(l_i, 32);
    float invl = 1.0f / l_i;

#pragma unroll
    for (int r = 0; r < 4; r++) {
      float inv = __shfl(invl, quad * 4 + r);   // lane whose col == quad*4+r
      size_t row = (size_t)(b * 2048 + qt * 64 + wave * 16 + quad * 4 + r);
#pragma unroll
      for (int nb = 0; nb < 4; nb++)
        ctx[row * 1024 + h * 64 + nb * 16 + col] = f2bf(o_acc[nb][r] * inv);
    }
  };

  process(p);          // qt_a = p        (p+1 ktiles)
  process(31 - p);     // qt_b = 31 - p   (32-p ktiles)  -> uniform 33 total
}

// ---------------------------------------------------------------------------
extern "C" void kernel_launch(void* const* d_in, const int* in_sizes, int n_in,
                              void* d_out, int out_size, void* d_ws, size_t ws_size,
                              hipStream_t stream) {
  const float* X  = (const float*)d_in[0];
  const int* pos  = (const int*)d_in[1];
  const float* wq = (const float*)d_in[2];
  const float* wk = (const float*)d_in[3];
  const float* wv = (const float*)d_in[4];
  const float* wo = (const float*)d_in[5];
  float* out = (float*)d_out;

  short* Xb  = (short*)d_ws;
  short* Wqb = Xb + (1 << 22);
  short* Wkb = Wqb + (1 << 20);
  short* Wvb = Wkb + (1 << 20);
  short* Wob = Wvb + (1 << 20);
  short* Qb  = Wob + (1 << 20);
  short* Kfb = Qb + (1 << 22);
  short* Vfb = Kfb + (1 << 22);
  short* Ctx = Vfb + (1 << 22);

  cast_all<<<8192, 256, 0, stream>>>((const float4*)X, (const float4*)wq, (const float4*)wk,
                                     (const float4*)wv, (const float4*)wo, Xb, Wqb);
  qkv_gemm<<<dim3(32, 8, 3), 256, 0, stream>>>(Xb, Wqb, Wkb, Wvb, Qb, Kfb, Vfb, pos);
  flash_attn<<<dim3(32, 16), 256, 0, stream>>>(Qb, Kfb, Vfb, Ctx);
  out_gemm<<<dim3(64, 8), 256, 0, stream>>>(Ctx, Wob, out);
}

// Round 2
// 173.104 us; speedup vs baseline: 1.0616x; 1.0165x over previous
//
#include <hip/hip_runtime.h>

// ---------------------------------------------------------------------------
// Multihead self-attention with RoPE, MI355X (gfx950).  Round 11.
// B=2, S=2048, H=16, DH=64, DM=1024.
// R11: flash_attn occupancy 2x. R10 counters: MfmaUtil 15%, VALUBusy 48%,
// HBM 6%, Occupancy 17.4% -> nothing saturated; grid (32,16)=512 blocks was
// exactly 2 blocks/CU (8 waves/CU = 25% cap). Fix: one qt per block, grid
// (32,32)=1024 blocks = 4 blocks/CU = 16 waves/CU, keeping 4-wave-per-(bh,qt)
// L1 sharing of K/V fragments (1-wave blocks would push ~40 TB/s onto L2 >
// 34.5 ceiling). R9's makespan hazard killed by balance-by-construction
// permutation: y->qt such that {y,y+8,y+16,y+24} (the RR co-residents) have
// qt summing 62 -> exactly 66 ktiles/CU; longest blocks (qt 31..24) dispatch
// first for LPT backfill under dynamic scheduling. launch_bounds(256,4).
// XCD pinning preserved: block%8 = bh%8 (same bh -> same XCD L2).
// R10 counted-vmcnt GEMM pipeline kept. qkv/out/cast untouched.
// ---------------------------------------------------------------------------

typedef __attribute__((ext_vector_type(8))) short bf16x8;
typedef __attribute__((ext_vector_type(4))) float f32x4;

__device__ __forceinline__ short f2bf(float f) {
  unsigned u = __float_as_uint(f);
  unsigned r = (u + 0x7fffu + ((u >> 16) & 1u)) >> 16;   // RNE
  return (short)(r & 0xFFFFu);
}

// pack two f32 -> adjacent bf16 (round-half-up via +0x8000), one v_perm_b32
__device__ __forceinline__ unsigned pk2(float a, float b) {
  return __builtin_amdgcn_perm(__float_as_uint(b) + 0x8000u,
                               __float_as_uint(a) + 0x8000u, 0x07060302u);
}

// async global->LDS, 16B per lane. LDS dest must be wave-uniform base + lane*16.
__device__ __forceinline__ void async16(const void* g, void* l) {
  __builtin_amdgcn_global_load_lds(
      (const __attribute__((address_space(1))) void*)g,
      (__attribute__((address_space(3))) void*)l, 16, 0, 0);
}

__device__ __forceinline__ void cstore(short* C, size_t i, float v) { C[i] = f2bf(v); }
__device__ __forceinline__ void cstore(float* C, size_t i, float v) { C[i] = v; }

// ---------------------------------------------------------------------------
// merged f32 -> bf16 cast: X (1M float4) then Wq|Wk|Wv|Wo (dsts contiguous).
// ---------------------------------------------------------------------------
__global__ void cast_all(const float4* __restrict__ X,
                         const float4* __restrict__ w0, const float4* __restrict__ w1,
                         const float4* __restrict__ w2, const float4* __restrict__ w3,
                         short* __restrict__ Xb, short* __restrict__ Wb) {
  int t = blockIdx.x * 256 + threadIdx.x;
  const float4* s;
  short4* d;
  if (t < (1 << 20)) {
    s = X + t; d = (short4*)Xb + t;
  } else {
    int u = t - (1 << 20);
    int which = u >> 18;
    s = ((which == 0) ? w0 : (which == 1) ? w1 : (which == 2) ? w2 : w3) + (u & 0x3FFFF);
    d = (short4*)Wb + u;
  }
  float4 v = *s;
  *d = make_short4(f2bf(v.x), f2bf(v.y), f2bf(v.z), f2bf(v.w));
}

// ---------------------------------------------------------------------------
// bf16 GEMM core: C[M,N] = A[M,K] * B[N,K]^T, K=1024, lda=ldb=1024.
// BM=32*MR, BN=32*NR; 4 waves 2x2. LDS passed in (3 buffers each for A,B).
// R10: 3-deep ring, prefetch 2 K-tiles ahead, counted vmcnt + raw s_barrier.
// Epilogue modes: EPI_ROW row-major; EPI_KFRAG / EPI_VFRAG fragment-major
// (per (b,h,kt,nb,half): 512-short segment in exact MFMA lane order).
// ---------------------------------------------------------------------------
enum EpiMode { EPI_ROW, EPI_KFRAG, EPI_VFRAG };

template <typename OUT, int MR, int NR, bool ROPE, EpiMode EM>
__device__ __forceinline__ void gemm_core(short* __restrict__ As, short* __restrict__ Bs,
                                          const short* __restrict__ A, const short* __restrict__ B,
                                          OUT* __restrict__ C, int bm, int bn, int ldc,
                                          const int* __restrict__ pos) {
  constexpr int BM = 32 * MR, BN = 32 * NR;
  constexpr int NLD = (BM * 4 + BN * 4) / 256;   // global_load_lds per wave per stage
  const int tid  = threadIdx.x;
  const int lane = tid & 63, wave = tid >> 6;
  const int col  = lane & 15, quad = lane >> 4;
  const int wm = (wave & 1) * (16 * MR), wn = (wave >> 1) * (16 * NR);

  f32x4 acc[MR][NR];
#pragma unroll
  for (int i = 0; i < MR; i++)
#pragma unroll
    for (int j = 0; j < NR; j++) acc[i][j] = (f32x4){0.f, 0.f, 0.f, 0.f};

  auto stage = [&](int k0, int bu) {
#pragma unroll
    for (int c = tid; c < BM * 4; c += 256) {
      int r = c >> 2, cc = (c & 3) << 3;
      async16(A + (size_t)(bm + r) * 1024 + k0 + cc, As + bu * BM * 32 + c * 8);
    }
#pragma unroll
    for (int c = tid; c < BN * 4; c += 256) {
      int r = c >> 2, cc = (c & 3) << 3;
      async16(B + (size_t)(bn + r) * 1024 + k0 + cc, Bs + bu * BN * 32 + c * 8);
    }
  };

  // prologue: 2 stages in flight, wait for stage 0 only (vmcnt leaves NLD).
  stage(0, 0);
  stage(32, 1);
  if constexpr (NLD == 4) asm volatile("s_waitcnt vmcnt(4)" ::: "memory");
  else                    asm volatile("s_waitcnt vmcnt(3)" ::: "memory");
  __builtin_amdgcn_s_barrier();

  int cur = 0, nxt = 2;
  for (int it = 0; it < 32; ++it) {
    if (it < 30) stage((it + 2) * 32, nxt);
    const short* as = As + cur * (BM * 32);
    const short* bs = Bs + cur * (BN * 32);

    bf16x8 af[MR], bfr[NR];
#pragma unroll
    for (int i = 0; i < MR; i++)
      af[i] = *(const bf16x8*)(as + (wm + i * 16 + col) * 32 + quad * 8);
#pragma unroll
    for (int i = 0; i < NR; i++)
      bfr[i] = *(const bf16x8*)(bs + (wn + i * 16 + col) * 32 + quad * 8);
#pragma unroll
    for (int mi = 0; mi < MR; mi++)
#pragma unroll
      for (int ni = 0; ni < NR; ni++)
        acc[mi][ni] = __builtin_amdgcn_mfma_f32_16x16x32_bf16(af[mi], bfr[ni], acc[mi][ni], 0, 0, 0);

    // counted drain: oldest stage (it+1) must have landed; newest (it+2) may fly.
    if (it < 30) {
      if constexpr (NLD == 4) asm volatile("s_waitcnt vmcnt(4)" ::: "memory");
      else                    asm volatile("s_waitcnt vmcnt(3)" ::: "memory");
    } else {
      asm volatile("s_waitcnt vmcnt(0)" ::: "memory");
    }
    __builtin_amdgcn_s_barrier();
    cur = (cur == 2) ? 0 : cur + 1;
    nxt = (nxt == 2) ? 0 : nxt + 1;
  }

  if (ROPE) {
    float invf_rev[NR];
#pragma unroll
    for (int ni = 0; ni < NR; ni++) {
      int pr = ((bn + wn + ni * 16 + col) & 63) >> 1;
      invf_rev[ni] = exp2f(-0.4152410118609203f * (float)pr) * 0.15915494309189535f;
    }
    const float sgn = (col & 1) ? 1.f : -1.f;
#pragma unroll
    for (int mi = 0; mi < MR; mi++) {
#pragma unroll
      for (int r = 0; r < 4; r++) {
        int row = bm + wm + mi * 16 + quad * 4 + r;
        float fp = (float)pos[row & 2047];
#pragma unroll
        for (int ni = 0; ni < NR; ni++) {
          float rev = fp * invf_rev[ni];
          rev -= floorf(rev);
          float sn = __builtin_amdgcn_sinf(rev);
          float cs = __builtin_amdgcn_cosf(rev);
          float x  = acc[mi][ni][r];
          float px = __shfl_xor(x, 1);
          acc[mi][ni][r] = fmaf(x, cs, sgn * px * sn);
        }
      }
    }
  }

  if (EM == EPI_ROW) {
#pragma unroll
    for (int mi = 0; mi < MR; mi++) {
#pragma unroll
      for (int r = 0; r < 4; r++) {
        size_t row = (size_t)(bm + wm + mi * 16 + quad * 4 + r);
#pragma unroll
        for (int ni = 0; ni < NR; ni++) {
          int cg = bn + wn + ni * 16 + col;
          cstore(C, row * ldc + cg, acc[mi][ni][r]);
        }
      }
    }
  } else if (EM == EPI_KFRAG) {
    // rows m = tokens, cols e = embed
#pragma unroll
    for (int mi = 0; mi < MR; mi++) {
#pragma unroll
      for (int r = 0; r < 4; r++) {
        int m = bm + wm + mi * 16 + quad * 4 + r;
        int bq = m >> 11, key = m & 2047;
        int kt = key >> 6, nb = (key >> 4) & 3, cl = key & 15;
#pragma unroll
        for (int ni = 0; ni < NR; ni++) {
          int e = bn + wn + ni * 16 + col;
          int h = e >> 6, d = e & 63;
          size_t seg = ((((size_t)(bq * 16 + h) * 32 + kt) * 4 + nb) * 2 + (d >> 5));
          cstore((short*)C, seg * 512 + (((d >> 3) & 3) * 16 + cl) * 8 + (d & 7), acc[mi][ni][r]);
        }
      }
    }
  } else {   // EPI_VFRAG: rows e = embed, cols m = tokens
#pragma unroll
    for (int mi = 0; mi < MR; mi++) {
#pragma unroll
      for (int r = 0; r < 4; r++) {
        int e = bm + wm + mi * 16 + quad * 4 + r;
        int h = e >> 6, d = e & 63;
        int nb = d >> 4, cl = d & 15;
#pragma unroll
        for (int ni = 0; ni < NR; ni++) {
          int m = bn + wn + ni * 16 + col;
          int bq = m >> 11, key = m & 2047;
          int kt = key >> 6, k64 = key & 63;
          size_t seg = ((((size_t)(bq * 16 + h) * 32 + kt) * 4 + nb) * 2 + (k64 >> 5));
          cstore((short*)C, seg * 512 + (((k64 >> 3) & 3) * 16 + cl) * 8 + (k64 & 7), acc[mi][ni][r]);
        }
      }
    }
  }
}

// z=0: Q = rope(X Wq^T) row-major; z=1: Kf = rope(X Wk^T) frag-major;
// z=2: Vf = Wv X^T frag-major.
__global__ __launch_bounds__(256, 3) void qkv_gemm(const short* __restrict__ Xb,
                                                   const short* __restrict__ Wq,
                                                   const short* __restrict__ Wk,
                                                   const short* __restrict__ Wv,
                                                   short* __restrict__ Qo,
                                                   short* __restrict__ Kf,
                                                   short* __restrict__ Vf,
                                                   const int* __restrict__ pos) {
  __shared__ __align__(16) short sm[3 * 128 * 32 + 3 * 128 * 32];   // 48 KB shared
  short* As = sm;
  short* Bs = sm + 3 * 128 * 32;
  const int z = blockIdx.z;
  if (z == 0)      gemm_core<short, 4, 4, true,  EPI_ROW  >(As, Bs, Xb, Wq, Qo, blockIdx.x * 128, blockIdx.y * 128, 1024, pos);
  else if (z == 1) gemm_core<short, 4, 4, true,  EPI_KFRAG>(As, Bs, Xb, Wk, Kf, blockIdx.x * 128, blockIdx.y * 128, 0, pos);
  else             gemm_core<short, 4, 4, false, EPI_VFRAG>(As, Bs, Wv, Xb, Vf, blockIdx.y * 128, blockIdx.x * 128, 0, pos);
}

__global__ __launch_bounds__(256) void out_gemm(const short* __restrict__ Ctx,
                                                const short* __restrict__ Wo,
                                                float* __restrict__ C) {
  __shared__ __align__(16) short sm[3 * 64 * 32 + 3 * 128 * 32];    // 36 KB
  gemm_core<float, 2, 4, false, EPI_ROW>(sm, sm + 3 * 64 * 32, Ctx, Wo, C,
                                         blockIdx.x * 64, blockIdx.y * 128, 1024, nullptr);
}

// ---------------------------------------------------------------------------
// Flash attention, causal. grid (bh=32, y=32), 256 threads = 4 INDEPENDENT
// waves (no __syncthreads), each wave = one 16-row strip of the block's
// single 64-row qtile. y->qt permutation: the 4 RR co-resident blocks
// {y, y+8, y+16, y+24} get qt summing 62 -> 66 ktiles/CU exactly; qt 31..24
// dispatch first (LPT). 4 blocks/CU = 16 waves/CU. Fragment-major K/V;
// register pipeline (vf at top, kf prefetched). Ps: stride-72 rows with
// XOR'd key chunks (nb ^ (col&3)).
// ---------------------------------------------------------------------------
__global__ __launch_bounds__(256, 4) void flash_attn(const short* __restrict__ Q,
                                                     const short* __restrict__ Kf,
                                                     const short* __restrict__ Vf,
                                                     short* __restrict__ ctx) {
  const int y = blockIdx.y;
  const int g = y >> 3, r8 = y & 7;
  const int qt = (g == 0) ? 31 - r8 : (g == 1) ? r8 : (g == 2) ? 23 - r8 : 8 + r8;
  const int bh = blockIdx.x;
  const int b = bh >> 4, h = bh & 15;
  __shared__ __align__(16) short Ps[4][16 * 72];         // per-wave P [q][key-chunk^]
  const int tid = threadIdx.x, lane = tid & 63, wave = tid >> 6;
  const int col = lane & 15, quad = lane >> 4;

  // fragment-major bases: bh covers 32 kt * 8 segs * 512 shorts = 131072
  const short* Kfb = Kf + (size_t)bh * 131072 + lane * 8;
  const short* Vfb = Vf + (size_t)bh * 131072 + lane * 8;

  const float C1 = 0.18033688011112042f;   // 0.125 * log2(e)
  const float C2 = 17.31234049066756f;     // 12 * log2(e)

  short* myPs = &Ps[wave][0];
  const int cx = col & 3;
  // write offsets per nb (xor-swizzled chunk), read offsets for af0/af1
  const int pswr0 = col * 72 + ((0 ^ cx) << 4) + quad * 4;
  const int pswr1 = col * 72 + ((1 ^ cx) << 4) + quad * 4;
  const int pswr2 = col * 72 + ((2 ^ cx) << 4) + quad * 4;
  const int pswr3 = col * 72 + ((3 ^ cx) << 4) + quad * 4;
  const int psrd0 = col * 72 + (((quad >> 1) ^ cx) << 4) + (quad & 1) * 8;
  const int psrd1 = col * 72 + ((((quad >> 1) + 2) ^ cx) << 4) + (quad & 1) * 8;

  auto ldk = [&](int kt, bf16x8 (&kf)[4][2]) {
    const int base = kt * 4096;
#pragma unroll
    for (int nb = 0; nb < 4; nb++) {
      kf[nb][0] = *(const bf16x8*)(Kfb + base + (nb * 2 + 0) * 512);
      kf[nb][1] = *(const bf16x8*)(Kfb + base + (nb * 2 + 1) * 512);
    }
  };
  auto ldv = [&](int kt, bf16x8 (&vf)[4][2]) {
    const int base = kt * 4096;
#pragma unroll
    for (int nb = 0; nb < 4; nb++) {
      vf[nb][0] = *(const bf16x8*)(Vfb + base + (nb * 2 + 0) * 512);
      vf[nb][1] = *(const bf16x8*)(Vfb + base + (nb * 2 + 1) * 512);
    }
  };

  // Q fragments (B-operand), one-time row-major gather
  const size_t qrow = (size_t)(b * 2048 + qt * 64 + wave * 16 + col);
  bf16x8 qf0 = *(const bf16x8*)(Q + qrow * 1024 + h * 64 + quad * 8);
  bf16x8 qf1 = *(const bf16x8*)(Q + qrow * 1024 + h * 64 + 32 + quad * 8);

  float l_i = 0.f;                                     // one q per lane (q=col)
  f32x4 o_acc[4];
#pragma unroll
  for (int i = 0; i < 4; i++) o_acc[i] = (f32x4){0.f, 0.f, 0.f, 0.f};

  const int qg = qt * 64 + wave * 16 + col;
  bf16x8 kf[4][2], vf[4][2];
  ldk(0, kf);

  for (int kt = 0; kt <= qt; ++kt) {
    // V for this tile: issued now, consumed at PV
    ldv(kt, vf);
    // S^T = K Q^T (kf prefetched last iteration)
    f32x4 s_acc[4];
#pragma unroll
    for (int nb = 0; nb < 4; nb++) {
      f32x4 z = (f32x4){0.f, 0.f, 0.f, 0.f};
      z = __builtin_amdgcn_mfma_f32_16x16x32_bf16(kf[nb][0], qf0, z, 0, 0, 0);
      z = __builtin_amdgcn_mfma_f32_16x16x32_bf16(kf[nb][1], qf1, z, 0, 0, 0);
      s_acc[nb] = z;
    }
    // prefetch next K
    if (kt < qt) ldk(kt + 1, kf);
    // softmax (fixed shift 12) + pack + b64 write (xor-swizzled chunk)
    const bool diag = (kt == qt);
#pragma unroll
    for (int nb = 0; nb < 4; nb++) {
      float pv[4];
#pragma unroll
      for (int r = 0; r < 4; r++) {
        pv[r] = exp2f(s_acc[nb][r] * C1 - C2);
        if (diag && (kt * 64 + nb * 16 + quad * 4 + r) > qg) pv[r] = 0.f;
        l_i += pv[r];
      }
      int wr = (nb == 0) ? pswr0 : (nb == 1) ? pswr1 : (nb == 2) ? pswr2 : pswr3;
      *(uint2*)(myPs + wr) = make_uint2(pk2(pv[0], pv[1]), pk2(pv[2], pv[3]));
    }
    // P fragment (A-op)
    bf16x8 af0 = *(const bf16x8*)(myPs + psrd0);
    bf16x8 af1 = *(const bf16x8*)(myPs + psrd1);
    // O += P V
#pragma unroll
    for (int nb = 0; nb < 4; nb++) {
      o_acc[nb] = __builtin_amdgcn_mfma_f32_16x16x32_bf16(af0, vf[nb][0], o_acc[nb], 0, 0, 0);
      o_acc[nb] = __builtin_amdgcn_mfma_f32_16x16x32_bf16(af1, vf[nb][1], o_acc[nb], 0, 0, 0);
    }
  }

  // l reduction over the 4 quads sharing this col
  l_i += __shfl_xor(l_i, 16);
  l_i += __shfl_xor(l_i, 32);
  float invl = 1.0f / l_i;

#pragma unroll
  for (int r = 0; r < 4; r++) {
    float inv = __shfl(invl, quad * 4 + r);   // lane whose col == quad*4+r
    size_t row = (size_t)(b * 2048 + qt * 64 + wave * 16 + quad * 4 + r);
#pragma unroll
    for (int nb = 0; nb < 4; nb++)
      ctx[row * 1024 + h * 64 + nb * 16 + col] = f2bf(o_acc[nb][r] * inv);
  }
}

// ---------------------------------------------------------------------------
extern "C" void kernel_launch(void* const* d_in, const int* in_sizes, int n_in,
                              void* d_out, int out_size, void* d_ws, size_t ws_size,
                              hipStream_t stream) {
  const float* X  = (const float*)d_in[0];
  const int* pos  = (const int*)d_in[1];
  const float* wq = (const float*)d_in[2];
  const float* wk = (const float*)d_in[3];
  const float* wv = (const float*)d_in[4];
  const float* wo = (const float*)d_in[5];
  float* out = (float*)d_out;

  short* Xb  = (short*)d_ws;
  short* Wqb = Xb + (1 << 22);
  short* Wkb = Wqb + (1 << 20);
  short* Wvb = Wkb + (1 << 20);
  short* Wob = Wvb + (1 << 20);
  short* Qb  = Wob + (1 << 20);
  short* Kfb = Qb + (1 << 22);
  short* Vfb = Kfb + (1 << 22);
  short* Ctx = Vfb + (1 << 22);

  cast_all<<<8192, 256, 0, stream>>>((const float4*)X, (const float4*)wq, (const float4*)wk,
                                     (const float4*)wv, (const float4*)wo, Xb, Wqb);
  qkv_gemm<<<dim3(32, 8, 3), 256, 0, stream>>>(Xb, Wqb, Wkb, Wvb, Qb, Kfb, Vfb, pos);
  flash_attn<<<dim3(32, 32), 256, 0, stream>>>(Qb, Kfb, Vfb, Ctx);
  out_gemm<<<dim3(64, 8), 256, 0, stream>>>(Ctx, Wob, out);
}

// Round 3
// 172.719 us; speedup vs baseline: 1.0639x; 1.0022x over previous
//
#include <hip/hip_runtime.h>

// ---------------------------------------------------------------------------
// Multihead self-attention with RoPE, MI355X (gfx950).  Round 12.
// B=2, S=2048, H=16, DH=64, DM=1024.
// R12: flash_attn K/V de-duplication through LDS. R11 A/B: doubling
// occupancy (17->27%) left duration pinned at 44 us, MfmaUtil 15%, VALUBusy
// 46% -> shared per-CU resource saturated = VMEM path: each of the 4 waves
// per block loaded the full 16 KB K+V tile per ktile = 1.08 GB in 44 us
// ~ 24.5 TB/s on the L1->L2 path (L1 thrashed: 4 blocks x 24 KB > 32 KiB).
// Fix: stage K/V once per block into LDS via global_load_lds (4 async16 per
// thread per ktile), double-buffered ring with counted vmcnt + raw
// s_barrier (one barrier + one vmcnt(0) per ktile; drain distance = full
// body > L2 latency). Waves read fragments via ds_read_b128 (lane*16B
// linear, conflict-free). Traffic 4x down. LDS 9216+32768=41984 B -> 3
// blocks/CU (12 waves). launch_bounds(256,3). LPT qt permutation kept.
// R10 counted-vmcnt GEMM pipeline kept. qkv/out/cast untouched.
// ---------------------------------------------------------------------------

typedef __attribute__((ext_vector_type(8))) short bf16x8;
typedef __attribute__((ext_vector_type(4))) float f32x4;

__device__ __forceinline__ short f2bf(float f) {
  unsigned u = __float_as_uint(f);
  unsigned r = (u + 0x7fffu + ((u >> 16) & 1u)) >> 16;   // RNE
  return (short)(r & 0xFFFFu);
}

// pack two f32 -> adjacent bf16 (round-half-up via +0x8000), one v_perm_b32
__device__ __forceinline__ unsigned pk2(float a, float b) {
  return __builtin_amdgcn_perm(__float_as_uint(b) + 0x8000u,
                               __float_as_uint(a) + 0x8000u, 0x07060302u);
}

// async global->LDS, 16B per lane. LDS dest must be wave-uniform base + lane*16.
__device__ __forceinline__ void async16(const void* g, void* l) {
  __builtin_amdgcn_global_load_lds(
      (const __attribute__((address_space(1))) void*)g,
      (__attribute__((address_space(3))) void*)l, 16, 0, 0);
}

__device__ __forceinline__ void cstore(short* C, size_t i, float v) { C[i] = f2bf(v); }
__device__ __forceinline__ void cstore(float* C, size_t i, float v) { C[i] = v; }

// ---------------------------------------------------------------------------
// merged f32 -> bf16 cast: X (1M float4) then Wq|Wk|Wv|Wo (dsts contiguous).
// ---------------------------------------------------------------------------
__global__ void cast_all(const float4* __restrict__ X,
                         const float4* __restrict__ w0, const float4* __restrict__ w1,
                         const float4* __restrict__ w2, const float4* __restrict__ w3,
                         short* __restrict__ Xb, short* __restrict__ Wb) {
  int t = blockIdx.x * 256 + threadIdx.x;
  const float4* s;
  short4* d;
  if (t < (1 << 20)) {
    s = X + t; d = (short4*)Xb + t;
  } else {
    int u = t - (1 << 20);
    int which = u >> 18;
    s = ((which == 0) ? w0 : (which == 1) ? w1 : (which == 2) ? w2 : w3) + (u & 0x3FFFF);
    d = (short4*)Wb + u;
  }
  float4 v = *s;
  *d = make_short4(f2bf(v.x), f2bf(v.y), f2bf(v.z), f2bf(v.w));
}

// ---------------------------------------------------------------------------
// bf16 GEMM core: C[M,N] = A[M,K] * B[N,K]^T, K=1024, lda=ldb=1024.
// BM=32*MR, BN=32*NR; 4 waves 2x2. LDS passed in (3 buffers each for A,B).
// R10: 3-deep ring, prefetch 2 K-tiles ahead, counted vmcnt + raw s_barrier.
// Epilogue modes: EPI_ROW row-major; EPI_KFRAG / EPI_VFRAG fragment-major
// (per (b,h,kt,nb,half): 512-short segment in exact MFMA lane order).
// ---------------------------------------------------------------------------
enum EpiMode { EPI_ROW, EPI_KFRAG, EPI_VFRAG };

template <typename OUT, int MR, int NR, bool ROPE, EpiMode EM>
__device__ __forceinline__ void gemm_core(short* __restrict__ As, short* __restrict__ Bs,
                                          const short* __restrict__ A, const short* __restrict__ B,
                                          OUT* __restrict__ C, int bm, int bn, int ldc,
                                          const int* __restrict__ pos) {
  constexpr int BM = 32 * MR, BN = 32 * NR;
  constexpr int NLD = (BM * 4 + BN * 4) / 256;   // global_load_lds per wave per stage
  const int tid  = threadIdx.x;
  const int lane = tid & 63, wave = tid >> 6;
  const int col  = lane & 15, quad = lane >> 4;
  const int wm = (wave & 1) * (16 * MR), wn = (wave >> 1) * (16 * NR);

  f32x4 acc[MR][NR];
#pragma unroll
  for (int i = 0; i < MR; i++)
#pragma unroll
    for (int j = 0; j < NR; j++) acc[i][j] = (f32x4){0.f, 0.f, 0.f, 0.f};

  auto stage = [&](int k0, int bu) {
#pragma unroll
    for (int c = tid; c < BM * 4; c += 256) {
      int r = c >> 2, cc = (c & 3) << 3;
      async16(A + (size_t)(bm + r) * 1024 + k0 + cc, As + bu * BM * 32 + c * 8);
    }
#pragma unroll
    for (int c = tid; c < BN * 4; c += 256) {
      int r = c >> 2, cc = (c & 3) << 3;
      async16(B + (size_t)(bn + r) * 1024 + k0 + cc, Bs + bu * BN * 32 + c * 8);
    }
  };

  // prologue: 2 stages in flight, wait for stage 0 only (vmcnt leaves NLD).
  stage(0, 0);
  stage(32, 1);
  if constexpr (NLD == 4) asm volatile("s_waitcnt vmcnt(4)" ::: "memory");
  else                    asm volatile("s_waitcnt vmcnt(3)" ::: "memory");
  __builtin_amdgcn_s_barrier();

  int cur = 0, nxt = 2;
  for (int it = 0; it < 32; ++it) {
    if (it < 30) stage((it + 2) * 32, nxt);
    const short* as = As + cur * (BM * 32);
    const short* bs = Bs + cur * (BN * 32);

    bf16x8 af[MR], bfr[NR];
#pragma unroll
    for (int i = 0; i < MR; i++)
      af[i] = *(const bf16x8*)(as + (wm + i * 16 + col) * 32 + quad * 8);
#pragma unroll
    for (int i = 0; i < NR; i++)
      bfr[i] = *(const bf16x8*)(bs + (wn + i * 16 + col) * 32 + quad * 8);
#pragma unroll
    for (int mi = 0; mi < MR; mi++)
#pragma unroll
      for (int ni = 0; ni < NR; ni++)
        acc[mi][ni] = __builtin_amdgcn_mfma_f32_16x16x32_bf16(af[mi], bfr[ni], acc[mi][ni], 0, 0, 0);

    // counted drain: oldest stage (it+1) must have landed; newest (it+2) may fly.
    if (it < 30) {
      if constexpr (NLD == 4) asm volatile("s_waitcnt vmcnt(4)" ::: "memory");
      else                    asm volatile("s_waitcnt vmcnt(3)" ::: "memory");
    } else {
      asm volatile("s_waitcnt vmcnt(0)" ::: "memory");
    }
    __builtin_amdgcn_s_barrier();
    cur = (cur == 2) ? 0 : cur + 1;
    nxt = (nxt == 2) ? 0 : nxt + 1;
  }

  if (ROPE) {
    float invf_rev[NR];
#pragma unroll
    for (int ni = 0; ni < NR; ni++) {
      int pr = ((bn + wn + ni * 16 + col) & 63) >> 1;
      invf_rev[ni] = exp2f(-0.4152410118609203f * (float)pr) * 0.15915494309189535f;
    }
    const float sgn = (col & 1) ? 1.f : -1.f;
#pragma unroll
    for (int mi = 0; mi < MR; mi++) {
#pragma unroll
      for (int r = 0; r < 4; r++) {
        int row = bm + wm + mi * 16 + quad * 4 + r;
        float fp = (float)pos[row & 2047];
#pragma unroll
        for (int ni = 0; ni < NR; ni++) {
          float rev = fp * invf_rev[ni];
          rev -= floorf(rev);
          float sn = __builtin_amdgcn_sinf(rev);
          float cs = __builtin_amdgcn_cosf(rev);
          float x  = acc[mi][ni][r];
          float px = __shfl_xor(x, 1);
          acc[mi][ni][r] = fmaf(x, cs, sgn * px * sn);
        }
      }
    }
  }

  if (EM == EPI_ROW) {
#pragma unroll
    for (int mi = 0; mi < MR; mi++) {
#pragma unroll
      for (int r = 0; r < 4; r++) {
        size_t row = (size_t)(bm + wm + mi * 16 + quad * 4 + r);
#pragma unroll
        for (int ni = 0; ni < NR; ni++) {
          int cg = bn + wn + ni * 16 + col;
          cstore(C, row * ldc + cg, acc[mi][ni][r]);
        }
      }
    }
  } else if (EM == EPI_KFRAG) {
    // rows m = tokens, cols e = embed
#pragma unroll
    for (int mi = 0; mi < MR; mi++) {
#pragma unroll
      for (int r = 0; r < 4; r++) {
        int m = bm + wm + mi * 16 + quad * 4 + r;
        int bq = m >> 11, key = m & 2047;
        int kt = key >> 6, nb = (key >> 4) & 3, cl = key & 15;
#pragma unroll
        for (int ni = 0; ni < NR; ni++) {
          int e = bn + wn + ni * 16 + col;
          int h = e >> 6, d = e & 63;
          size_t seg = ((((size_t)(bq * 16 + h) * 32 + kt) * 4 + nb) * 2 + (d >> 5));
          cstore((short*)C, seg * 512 + (((d >> 3) & 3) * 16 + cl) * 8 + (d & 7), acc[mi][ni][r]);
        }
      }
    }
  } else {   // EPI_VFRAG: rows e = embed, cols m = tokens
#pragma unroll
    for (int mi = 0; mi < MR; mi++) {
#pragma unroll
      for (int r = 0; r < 4; r++) {
        int e = bm + wm + mi * 16 + quad * 4 + r;
        int h = e >> 6, d = e & 63;
        int nb = d >> 4, cl = d & 15;
#pragma unroll
        for (int ni = 0; ni < NR; ni++) {
          int m = bn + wn + ni * 16 + col;
          int bq = m >> 11, key = m & 2047;
          int kt = key >> 6, k64 = key & 63;
          size_t seg = ((((size_t)(bq * 16 + h) * 32 + kt) * 4 + nb) * 2 + (k64 >> 5));
          cstore((short*)C, seg * 512 + (((k64 >> 3) & 3) * 16 + cl) * 8 + (k64 & 7), acc[mi][ni][r]);
        }
      }
    }
  }
}

// z=0: Q = rope(X Wq^T) row-major; z=1: Kf = rope(X Wk^T) frag-major;
// z=2: Vf = Wv X^T frag-major.
__global__ __launch_bounds__(256, 3) void qkv_gemm(const short* __restrict__ Xb,
                                                   const short* __restrict__ Wq,
                                                   const short* __restrict__ Wk,
                                                   const short* __restrict__ Wv,
                                                   short* __restrict__ Qo,
                                                   short* __restrict__ Kf,
                                                   short* __restrict__ Vf,
                                                   const int* __restrict__ pos) {
  __shared__ __align__(16) short sm[3 * 128 * 32 + 3 * 128 * 32];   // 48 KB shared
  short* As = sm;
  short* Bs = sm + 3 * 128 * 32;
  const int z = blockIdx.z;
  if (z == 0)      gemm_core<short, 4, 4, true,  EPI_ROW  >(As, Bs, Xb, Wq, Qo, blockIdx.x * 128, blockIdx.y * 128, 1024, pos);
  else if (z == 1) gemm_core<short, 4, 4, true,  EPI_KFRAG>(As, Bs, Xb, Wk, Kf, blockIdx.x * 128, blockIdx.y * 128, 0, pos);
  else             gemm_core<short, 4, 4, false, EPI_VFRAG>(As, Bs, Wv, Xb, Vf, blockIdx.y * 128, blockIdx.x * 128, 0, pos);
}

__global__ __launch_bounds__(256) void out_gemm(const short* __restrict__ Ctx,
                                                const short* __restrict__ Wo,
                                                float* __restrict__ C) {
  __shared__ __align__(16) short sm[3 * 64 * 32 + 3 * 128 * 32];    // 36 KB
  gemm_core<float, 2, 4, false, EPI_ROW>(sm, sm + 3 * 64 * 32, Ctx, Wo, C,
                                         blockIdx.x * 64, blockIdx.y * 128, 1024, nullptr);
}

// ---------------------------------------------------------------------------
// Flash attention, causal. grid (bh=32, y=32), 256 threads = 4 waves, each
// wave = one 16-row strip of the block's single 64-row qtile. R12: K/V tile
// (8 KB each) staged ONCE per block into LDS (global_load_lds, 4 async16 per
// thread per ktile), double-buffered; one vmcnt(0) + s_barrier per ktile.
// All 4 waves read fragments from LDS (ds_read_b128, lane*16B linear).
// y->qt LPT permutation kept. 3 blocks/CU. Ps: stride-72 rows with XOR'd
// key chunks (nb ^ (col&3)).
// ---------------------------------------------------------------------------
__global__ __launch_bounds__(256, 3) void flash_attn(const short* __restrict__ Q,
                                                     const short* __restrict__ Kf,
                                                     const short* __restrict__ Vf,
                                                     short* __restrict__ ctx) {
  const int y = blockIdx.y;
  const int g = y >> 3, r8 = y & 7;
  const int qt = (g == 0) ? 31 - r8 : (g == 1) ? r8 : (g == 2) ? 23 - r8 : 8 + r8;
  const int bh = blockIdx.x;
  const int b = bh >> 4, h = bh & 15;
  __shared__ __align__(16) short Ps[4][16 * 72];         // per-wave P [q][key-chunk^]
  __shared__ __align__(16) short Ksm[2][4096];           // 8 KB per buffer
  __shared__ __align__(16) short Vsm[2][4096];
  const int tid = threadIdx.x, lane = tid & 63, wave = tid >> 6;
  const int col = lane & 15, quad = lane >> 4;

  // fragment-major global bases: bh covers 32 kt * 8 segs * 512 shorts
  const short* Kg = Kf + (size_t)bh * 131072;
  const short* Vg = Vf + (size_t)bh * 131072;

  const float C1 = 0.18033688011112042f;   // 0.125 * log2(e)
  const float C2 = 17.31234049066756f;     // 12 * log2(e)

  short* myPs = &Ps[wave][0];
  const int cx = col & 3;
  // write offsets per nb (xor-swizzled chunk), read offsets for af0/af1
  const int pswr0 = col * 72 + ((0 ^ cx) << 4) + quad * 4;
  const int pswr1 = col * 72 + ((1 ^ cx) << 4) + quad * 4;
  const int pswr2 = col * 72 + ((2 ^ cx) << 4) + quad * 4;
  const int pswr3 = col * 72 + ((3 ^ cx) << 4) + quad * 4;
  const int psrd0 = col * 72 + (((quad >> 1) ^ cx) << 4) + (quad & 1) * 8;
  const int psrd1 = col * 72 + ((((quad >> 1) + 2) ^ cx) << 4) + (quad & 1) * 8;

  // stage K/V tile kt into buffer bu: 512 chunks of 16B each for K and V;
  // 256 threads -> 2 chunks each per array (4 async16 total per thread).
  auto stageKV = [&](int kt, int bu) {
    const short* kg = Kg + kt * 4096;
    const short* vg = Vg + kt * 4096;
#pragma unroll
    for (int c = tid; c < 512; c += 256) {
      async16(kg + c * 8, &Ksm[bu][c * 8]);
      async16(vg + c * 8, &Vsm[bu][c * 8]);
    }
  };

  // Q fragments (B-operand), one-time row-major gather
  const size_t qrow = (size_t)(b * 2048 + qt * 64 + wave * 16 + col);
  bf16x8 qf0 = *(const bf16x8*)(Q + qrow * 1024 + h * 64 + quad * 8);
  bf16x8 qf1 = *(const bf16x8*)(Q + qrow * 1024 + h * 64 + 32 + quad * 8);

  float l_i = 0.f;                                     // one q per lane (q=col)
  f32x4 o_acc[4];
#pragma unroll
  for (int i = 0; i < 4; i++) o_acc[i] = (f32x4){0.f, 0.f, 0.f, 0.f};

  const int qg = qt * 64 + wave * 16 + col;

  stageKV(0, 0);
  asm volatile("s_waitcnt vmcnt(0)" ::: "memory");
  __builtin_amdgcn_s_barrier();

  for (int kt = 0; kt <= qt; ++kt) {
    const int cur = kt & 1;
    // prefetch next tile into the other buffer (last read at kt-1, behind barrier)
    if (kt < qt) stageKV(kt + 1, cur ^ 1);

    // fragments from LDS (linear lane*16B within each 1 KB segment)
    bf16x8 kfr[4][2], vfr[4][2];
#pragma unroll
    for (int nb = 0; nb < 4; nb++) {
      kfr[nb][0] = *(const bf16x8*)(&Ksm[cur][(nb * 2 + 0) * 512] + lane * 8);
      kfr[nb][1] = *(const bf16x8*)(&Ksm[cur][(nb * 2 + 1) * 512] + lane * 8);
      vfr[nb][0] = *(const bf16x8*)(&Vsm[cur][(nb * 2 + 0) * 512] + lane * 8);
      vfr[nb][1] = *(const bf16x8*)(&Vsm[cur][(nb * 2 + 1) * 512] + lane * 8);
    }

    // S^T = K Q^T
    f32x4 s_acc[4];
#pragma unroll
    for (int nb = 0; nb < 4; nb++) {
      f32x4 z = (f32x4){0.f, 0.f, 0.f, 0.f};
      z = __builtin_amdgcn_mfma_f32_16x16x32_bf16(kfr[nb][0], qf0, z, 0, 0, 0);
      z = __builtin_amdgcn_mfma_f32_16x16x32_bf16(kfr[nb][1], qf1, z, 0, 0, 0);
      s_acc[nb] = z;
    }

    // softmax (fixed shift 12) + pack + b64 write (xor-swizzled chunk)
    const bool diag = (kt == qt);
#pragma unroll
    for (int nb = 0; nb < 4; nb++) {
      float pv[4];
#pragma unroll
      for (int r = 0; r < 4; r++) {
        pv[r] = exp2f(s_acc[nb][r] * C1 - C2);
        if (diag && (kt * 64 + nb * 16 + quad * 4 + r) > qg) pv[r] = 0.f;
        l_i += pv[r];
      }
      int wr = (nb == 0) ? pswr0 : (nb == 1) ? pswr1 : (nb == 2) ? pswr2 : pswr3;
      *(uint2*)(myPs + wr) = make_uint2(pk2(pv[0], pv[1]), pk2(pv[2], pv[3]));
    }
    // P fragment (A-op)
    bf16x8 af0 = *(const bf16x8*)(myPs + psrd0);
    bf16x8 af1 = *(const bf16x8*)(myPs + psrd1);
    // O += P V
#pragma unroll
    for (int nb = 0; nb < 4; nb++) {
      o_acc[nb] = __builtin_amdgcn_mfma_f32_16x16x32_bf16(af0, vfr[nb][0], o_acc[nb], 0, 0, 0);
      o_acc[nb] = __builtin_amdgcn_mfma_f32_16x16x32_bf16(af1, vfr[nb][1], o_acc[nb], 0, 0, 0);
    }

    // all this wave's ds_reads retired (consumed by MFMAs above); drain the
    // prefetch and barrier so next iter may read buf[cur^1] and overwrite
    // buf[cur] at kt+1's stage.
    if (kt < qt) {
      asm volatile("s_waitcnt vmcnt(0)" ::: "memory");
      __builtin_amdgcn_s_barrier();
    }
  }

  // l reduction over the 4 quads sharing this col
  l_i += __shfl_xor(l_i, 16);
  l_i += __shfl_xor(l_i, 32);
  float invl = 1.0f / l_i;

#pragma unroll
  for (int r = 0; r < 4; r++) {
    float inv = __shfl(invl, quad * 4 + r);   // lane whose col == quad*4+r
    size_t row = (size_t)(b * 2048 + qt * 64 + wave * 16 + quad * 4 + r);
#pragma unroll
    for (int nb = 0; nb < 4; nb++)
      ctx[row * 1024 + h * 64 + nb * 16 + col] = f2bf(o_acc[nb][r] * inv);
  }
}

// ---------------------------------------------------------------------------
extern "C" void kernel_launch(void* const* d_in, const int* in_sizes, int n_in,
                              void* d_out, int out_size, void* d_ws, size_t ws_size,
                              hipStream_t stream) {
  const float* X  = (const float*)d_in[0];
  const int* pos  = (const int*)d_in[1];
  const float* wq = (const float*)d_in[2];
  const float* wk = (const float*)d_in[3];
  const float* wv = (const float*)d_in[4];
  const float* wo = (const float*)d_in[5];
  float* out = (float*)d_out;

  short* Xb  = (short*)d_ws;
  short* Wqb = Xb + (1 << 22);
  short* Wkb = Wqb + (1 << 20);
  short* Wvb = Wkb + (1 << 20);
  short* Wob = Wvb + (1 << 20);
  short* Qb  = Wob + (1 << 20);
  short* Kfb = Qb + (1 << 22);
  short* Vfb = Kfb + (1 << 22);
  short* Ctx = Vfb + (1 << 22);

  cast_all<<<8192, 256, 0, stream>>>((const float4*)X, (const float4*)wq, (const float4*)wk,
                                     (const float4*)wv, (const float4*)wo, Xb, Wqb);
  qkv_gemm<<<dim3(32, 8, 3), 256, 0, stream>>>(Xb, Wqb, Wkb, Wvb, Qb, Kfb, Vfb, pos);
  flash_attn<<<dim3(32, 32), 256, 0, stream>>>(Qb, Kfb, Vfb, Ctx);
  out_gemm<<<dim3(64, 8), 256, 0, stream>>>(Ctx, Wob, out);
}

// Round 4
// 167.796 us; speedup vs baseline: 1.0951x; 1.0293x over previous
//
#include <hip/hip_runtime.h>

// ---------------------------------------------------------------------------
// Multihead self-attention with RoPE, MI355X (gfx950).  Round 13.
// B=2, S=2048, H=16, DH=64, DM=1024.
// R13: flash_attn instruction diet. R10-R12 invariant: flash pinned at
// ~44.4 us across occupancy 17->27%, traffic 4x cut, barrier add -> wall =
// longest block (32 ktiles) x ~3300 cyc/ktile; per-ktile = ~3 waves/SIMD x
// ~800 issue-cyc + bubbles = issue-port contention. VALU measured ~2.5x the
// naive source count: diag mask evaluated every ktile (~60 VALU), exp2f
// expanding to guarded OCML (~6 ops ea), serial l_i chain, per-iter buffer
// index math. Diet: (1) peel diag ktile - main loop maskless; (2) inline-asm
// v_exp_f32 (native 2^x, 1 instr); (3) l_i tree adds; (4) two-pointer
// Ksm/Vsm swap. Issue/wave-ktile ~800 -> ~450. Grid/LPT/LDS staging kept.
// qkv/out/cast untouched for attribution.
// ---------------------------------------------------------------------------

typedef __attribute__((ext_vector_type(8))) short bf16x8;
typedef __attribute__((ext_vector_type(4))) float f32x4;

__device__ __forceinline__ short f2bf(float f) {
  unsigned u = __float_as_uint(f);
  unsigned r = (u + 0x7fffu + ((u >> 16) & 1u)) >> 16;   // RNE
  return (short)(r & 0xFFFFu);
}

// pack two f32 -> adjacent bf16 (round-half-up via +0x8000), one v_perm_b32
__device__ __forceinline__ unsigned pk2(float a, float b) {
  return __builtin_amdgcn_perm(__float_as_uint(b) + 0x8000u,
                               __float_as_uint(a) + 0x8000u, 0x07060302u);
}

// native 2^x, one v_exp_f32 (bypasses OCML guard sequence)
__device__ __forceinline__ float exp2x(float x) {
  float r;
  asm("v_exp_f32 %0, %1" : "=v"(r) : "v"(x));
  return r;
}

// async global->LDS, 16B per lane. LDS dest must be wave-uniform base + lane*16.
__device__ __forceinline__ void async16(const void* g, void* l) {
  __builtin_amdgcn_global_load_lds(
      (const __attribute__((address_space(1))) void*)g,
      (__attribute__((address_space(3))) void*)l, 16, 0, 0);
}

__device__ __forceinline__ void cstore(short* C, size_t i, float v) { C[i] = f2bf(v); }
__device__ __forceinline__ void cstore(float* C, size_t i, float v) { C[i] = v; }

// ---------------------------------------------------------------------------
// merged f32 -> bf16 cast: X (1M float4) then Wq|Wk|Wv|Wo (dsts contiguous).
// ---------------------------------------------------------------------------
__global__ void cast_all(const float4* __restrict__ X,
                         const float4* __restrict__ w0, const float4* __restrict__ w1,
                         const float4* __restrict__ w2, const float4* __restrict__ w3,
                         short* __restrict__ Xb, short* __restrict__ Wb) {
  int t = blockIdx.x * 256 + threadIdx.x;
  const float4* s;
  short4* d;
  if (t < (1 << 20)) {
    s = X + t; d = (short4*)Xb + t;
  } else {
    int u = t - (1 << 20);
    int which = u >> 18;
    s = ((which == 0) ? w0 : (which == 1) ? w1 : (which == 2) ? w2 : w3) + (u & 0x3FFFF);
    d = (short4*)Wb + u;
  }
  float4 v = *s;
  *d = make_short4(f2bf(v.x), f2bf(v.y), f2bf(v.z), f2bf(v.w));
}

// ---------------------------------------------------------------------------
// bf16 GEMM core: C[M,N] = A[M,K] * B[N,K]^T, K=1024, lda=ldb=1024.
// BM=32*MR, BN=32*NR; 4 waves 2x2. LDS passed in (3 buffers each for A,B).
// R10: 3-deep ring, prefetch 2 K-tiles ahead, counted vmcnt + raw s_barrier.
// Epilogue modes: EPI_ROW row-major; EPI_KFRAG / EPI_VFRAG fragment-major
// (per (b,h,kt,nb,half): 512-short segment in exact MFMA lane order).
// ---------------------------------------------------------------------------
enum EpiMode { EPI_ROW, EPI_KFRAG, EPI_VFRAG };

template <typename OUT, int MR, int NR, bool ROPE, EpiMode EM>
__device__ __forceinline__ void gemm_core(short* __restrict__ As, short* __restrict__ Bs,
                                          const short* __restrict__ A, const short* __restrict__ B,
                                          OUT* __restrict__ C, int bm, int bn, int ldc,
                                          const int* __restrict__ pos) {
  constexpr int BM = 32 * MR, BN = 32 * NR;
  constexpr int NLD = (BM * 4 + BN * 4) / 256;   // global_load_lds per wave per stage
  const int tid  = threadIdx.x;
  const int lane = tid & 63, wave = tid >> 6;
  const int col  = lane & 15, quad = lane >> 4;
  const int wm = (wave & 1) * (16 * MR), wn = (wave >> 1) * (16 * NR);

  f32x4 acc[MR][NR];
#pragma unroll
  for (int i = 0; i < MR; i++)
#pragma unroll
    for (int j = 0; j < NR; j++) acc[i][j] = (f32x4){0.f, 0.f, 0.f, 0.f};

  auto stage = [&](int k0, int bu) {
#pragma unroll
    for (int c = tid; c < BM * 4; c += 256) {
      int r = c >> 2, cc = (c & 3) << 3;
      async16(A + (size_t)(bm + r) * 1024 + k0 + cc, As + bu * BM * 32 + c * 8);
    }
#pragma unroll
    for (int c = tid; c < BN * 4; c += 256) {
      int r = c >> 2, cc = (c & 3) << 3;
      async16(B + (size_t)(bn + r) * 1024 + k0 + cc, Bs + bu * BN * 32 + c * 8);
    }
  };

  // prologue: 2 stages in flight, wait for stage 0 only (vmcnt leaves NLD).
  stage(0, 0);
  stage(32, 1);
  if constexpr (NLD == 4) asm volatile("s_waitcnt vmcnt(4)" ::: "memory");
  else                    asm volatile("s_waitcnt vmcnt(3)" ::: "memory");
  __builtin_amdgcn_s_barrier();

  int cur = 0, nxt = 2;
  for (int it = 0; it < 32; ++it) {
    if (it < 30) stage((it + 2) * 32, nxt);
    const short* as = As + cur * (BM * 32);
    const short* bs = Bs + cur * (BN * 32);

    bf16x8 af[MR], bfr[NR];
#pragma unroll
    for (int i = 0; i < MR; i++)
      af[i] = *(const bf16x8*)(as + (wm + i * 16 + col) * 32 + quad * 8);
#pragma unroll
    for (int i = 0; i < NR; i++)
      bfr[i] = *(const bf16x8*)(bs + (wn + i * 16 + col) * 32 + quad * 8);
#pragma unroll
    for (int mi = 0; mi < MR; mi++)
#pragma unroll
      for (int ni = 0; ni < NR; ni++)
        acc[mi][ni] = __builtin_amdgcn_mfma_f32_16x16x32_bf16(af[mi], bfr[ni], acc[mi][ni], 0, 0, 0);

    // counted drain: oldest stage (it+1) must have landed; newest (it+2) may fly.
    if (it < 30) {
      if constexpr (NLD == 4) asm volatile("s_waitcnt vmcnt(4)" ::: "memory");
      else                    asm volatile("s_waitcnt vmcnt(3)" ::: "memory");
    } else {
      asm volatile("s_waitcnt vmcnt(0)" ::: "memory");
    }
    __builtin_amdgcn_s_barrier();
    cur = (cur == 2) ? 0 : cur + 1;
    nxt = (nxt == 2) ? 0 : nxt + 1;
  }

  if (ROPE) {
    float invf_rev[NR];
#pragma unroll
    for (int ni = 0; ni < NR; ni++) {
      int pr = ((bn + wn + ni * 16 + col) & 63) >> 1;
      invf_rev[ni] = exp2f(-0.4152410118609203f * (float)pr) * 0.15915494309189535f;
    }
    const float sgn = (col & 1) ? 1.f : -1.f;
#pragma unroll
    for (int mi = 0; mi < MR; mi++) {
#pragma unroll
      for (int r = 0; r < 4; r++) {
        int row = bm + wm + mi * 16 + quad * 4 + r;
        float fp = (float)pos[row & 2047];
#pragma unroll
        for (int ni = 0; ni < NR; ni++) {
          float rev = fp * invf_rev[ni];
          rev -= floorf(rev);
          float sn = __builtin_amdgcn_sinf(rev);
          float cs = __builtin_amdgcn_cosf(rev);
          float x  = acc[mi][ni][r];
          float px = __shfl_xor(x, 1);
          acc[mi][ni][r] = fmaf(x, cs, sgn * px * sn);
        }
      }
    }
  }

  if (EM == EPI_ROW) {
#pragma unroll
    for (int mi = 0; mi < MR; mi++) {
#pragma unroll
      for (int r = 0; r < 4; r++) {
        size_t row = (size_t)(bm + wm + mi * 16 + quad * 4 + r);
#pragma unroll
        for (int ni = 0; ni < NR; ni++) {
          int cg = bn + wn + ni * 16 + col;
          cstore(C, row * ldc + cg, acc[mi][ni][r]);
        }
      }
    }
  } else if (EM == EPI_KFRAG) {
    // rows m = tokens, cols e = embed
#pragma unroll
    for (int mi = 0; mi < MR; mi++) {
#pragma unroll
      for (int r = 0; r < 4; r++) {
        int m = bm + wm + mi * 16 + quad * 4 + r;
        int bq = m >> 11, key = m & 2047;
        int kt = key >> 6, nb = (key >> 4) & 3, cl = key & 15;
#pragma unroll
        for (int ni = 0; ni < NR; ni++) {
          int e = bn + wn + ni * 16 + col;
          int h = e >> 6, d = e & 63;
          size_t seg = ((((size_t)(bq * 16 + h) * 32 + kt) * 4 + nb) * 2 + (d >> 5));
          cstore((short*)C, seg * 512 + (((d >> 3) & 3) * 16 + cl) * 8 + (d & 7), acc[mi][ni][r]);
        }
      }
    }
  } else {   // EPI_VFRAG: rows e = embed, cols m = tokens
#pragma unroll
    for (int mi = 0; mi < MR; mi++) {
#pragma unroll
      for (int r = 0; r < 4; r++) {
        int e = bm + wm + mi * 16 + quad * 4 + r;
        int h = e >> 6, d = e & 63;
        int nb = d >> 4, cl = d & 15;
#pragma unroll
        for (int ni = 0; ni < NR; ni++) {
          int m = bn + wn + ni * 16 + col;
          int bq = m >> 11, key = m & 2047;
          int kt = key >> 6, k64 = key & 63;
          size_t seg = ((((size_t)(bq * 16 + h) * 32 + kt) * 4 + nb) * 2 + (k64 >> 5));
          cstore((short*)C, seg * 512 + (((k64 >> 3) & 3) * 16 + cl) * 8 + (k64 & 7), acc[mi][ni][r]);
        }
      }
    }
  }
}

// z=0: Q = rope(X Wq^T) row-major; z=1: Kf = rope(X Wk^T) frag-major;
// z=2: Vf = Wv X^T frag-major.
__global__ __launch_bounds__(256, 3) void qkv_gemm(const short* __restrict__ Xb,
                                                   const short* __restrict__ Wq,
                                                   const short* __restrict__ Wk,
                                                   const short* __restrict__ Wv,
                                                   short* __restrict__ Qo,
                                                   short* __restrict__ Kf,
                                                   short* __restrict__ Vf,
                                                   const int* __restrict__ pos) {
  __shared__ __align__(16) short sm[3 * 128 * 32 + 3 * 128 * 32];   // 48 KB shared
  short* As = sm;
  short* Bs = sm + 3 * 128 * 32;
  const int z = blockIdx.z;
  if (z == 0)      gemm_core<short, 4, 4, true,  EPI_ROW  >(As, Bs, Xb, Wq, Qo, blockIdx.x * 128, blockIdx.y * 128, 1024, pos);
  else if (z == 1) gemm_core<short, 4, 4, true,  EPI_KFRAG>(As, Bs, Xb, Wk, Kf, blockIdx.x * 128, blockIdx.y * 128, 0, pos);
  else             gemm_core<short, 4, 4, false, EPI_VFRAG>(As, Bs, Wv, Xb, Vf, blockIdx.y * 128, blockIdx.x * 128, 0, pos);
}

__global__ __launch_bounds__(256) void out_gemm(const short* __restrict__ Ctx,
                                                const short* __restrict__ Wo,
                                                float* __restrict__ C) {
  __shared__ __align__(16) short sm[3 * 64 * 32 + 3 * 128 * 32];    // 36 KB
  gemm_core<float, 2, 4, false, EPI_ROW>(sm, sm + 3 * 64 * 32, Ctx, Wo, C,
                                         blockIdx.x * 64, blockIdx.y * 128, 1024, nullptr);
}

// ---------------------------------------------------------------------------
// Flash attention, causal. grid (bh=32, y=32), 256 threads = 4 waves, each
// wave = one 16-row strip of the block's single 64-row qtile. K/V staged
// once per block into LDS (double-buffered, vmcnt(0)+s_barrier per ktile).
// R13: maskless main loop (diag ktile peeled), native v_exp_f32, l_i tree
// adds, two-pointer K/V buffer swap. y->qt LPT permutation kept. 3
// blocks/CU. Ps: stride-72 rows with XOR'd key chunks (nb ^ (col&3)).
// ---------------------------------------------------------------------------
__global__ __launch_bounds__(256, 3) void flash_attn(const short* __restrict__ Q,
                                                     const short* __restrict__ Kf,
                                                     const short* __restrict__ Vf,
                                                     short* __restrict__ ctx) {
  const int y = blockIdx.y;
  const int g = y >> 3, r8 = y & 7;
  const int qt = (g == 0) ? 31 - r8 : (g == 1) ? r8 : (g == 2) ? 23 - r8 : 8 + r8;
  const int bh = blockIdx.x;
  const int b = bh >> 4, h = bh & 15;
  __shared__ __align__(16) short Ps[4][16 * 72];         // per-wave P [q][key-chunk^]
  __shared__ __align__(16) short Ksm[2][4096];           // 8 KB per buffer
  __shared__ __align__(16) short Vsm[2][4096];
  const int tid = threadIdx.x, lane = tid & 63, wave = tid >> 6;
  const int col = lane & 15, quad = lane >> 4;

  // fragment-major global bases: bh covers 32 kt * 8 segs * 512 shorts
  const short* Kg = Kf + (size_t)bh * 131072;
  const short* Vg = Vf + (size_t)bh * 131072;

  const float C1 = 0.18033688011112042f;    // 0.125 * log2(e)
  const float mC2 = -17.31234049066756f;    // -12 * log2(e)

  short* myPs = &Ps[wave][0];
  const int cx = col & 3;
  // write offsets per nb (xor-swizzled chunk), read offsets for af0/af1
  const int pswr0 = col * 72 + ((0 ^ cx) << 4) + quad * 4;
  const int pswr1 = col * 72 + ((1 ^ cx) << 4) + quad * 4;
  const int pswr2 = col * 72 + ((2 ^ cx) << 4) + quad * 4;
  const int pswr3 = col * 72 + ((3 ^ cx) << 4) + quad * 4;
  const int psrd0 = col * 72 + (((quad >> 1) ^ cx) << 4) + (quad & 1) * 8;
  const int psrd1 = col * 72 + ((((quad >> 1) + 2) ^ cx) << 4) + (quad & 1) * 8;

  // stage K/V tile kt into buffer bu: 512 chunks of 16B each for K and V.
  auto stageKV = [&](int kt, short* kb, short* vb) {
    const short* kg = Kg + kt * 4096;
    const short* vg = Vg + kt * 4096;
#pragma unroll
    for (int c = tid; c < 512; c += 256) {
      async16(kg + c * 8, kb + c * 8);
      async16(vg + c * 8, vb + c * 8);
    }
  };

  // Q fragments (B-operand), one-time row-major gather
  const size_t qrow = (size_t)(b * 2048 + qt * 64 + wave * 16 + col);
  bf16x8 qf0 = *(const bf16x8*)(Q + qrow * 1024 + h * 64 + quad * 8);
  bf16x8 qf1 = *(const bf16x8*)(Q + qrow * 1024 + h * 64 + 32 + quad * 8);

  float l_i = 0.f;                                     // one q per lane (q=col)
  f32x4 o_acc[4];
#pragma unroll
  for (int i = 0; i < 4; i++) o_acc[i] = (f32x4){0.f, 0.f, 0.f, 0.f};

  short *kcur = &Ksm[0][0], *vcur = &Vsm[0][0];
  short *knxt = &Ksm[1][0], *vnxt = &Vsm[1][0];

  stageKV(0, kcur, vcur);
  asm volatile("s_waitcnt vmcnt(0)" ::: "memory");
  __builtin_amdgcn_s_barrier();

  // -------- main loop: NO masking (diag ktile peeled) --------
  for (int kt = 0; kt < qt; ++kt) {
    stageKV(kt + 1, knxt, vnxt);

    bf16x8 kfr[4][2], vfr[4][2];
#pragma unroll
    for (int nb = 0; nb < 4; nb++) {
      kfr[nb][0] = *(const bf16x8*)(kcur + (nb * 2 + 0) * 512 + lane * 8);
      kfr[nb][1] = *(const bf16x8*)(kcur + (nb * 2 + 1) * 512 + lane * 8);
      vfr[nb][0] = *(const bf16x8*)(vcur + (nb * 2 + 0) * 512 + lane * 8);
      vfr[nb][1] = *(const bf16x8*)(vcur + (nb * 2 + 1) * 512 + lane * 8);
    }

    f32x4 s_acc[4];
#pragma unroll
    for (int nb = 0; nb < 4; nb++) {
      f32x4 z = (f32x4){0.f, 0.f, 0.f, 0.f};
      z = __builtin_amdgcn_mfma_f32_16x16x32_bf16(kfr[nb][0], qf0, z, 0, 0, 0);
      z = __builtin_amdgcn_mfma_f32_16x16x32_bf16(kfr[nb][1], qf1, z, 0, 0, 0);
      s_acc[nb] = z;
    }

#pragma unroll
    for (int nb = 0; nb < 4; nb++) {
      float p0 = exp2x(fmaf(s_acc[nb][0], C1, mC2));
      float p1 = exp2x(fmaf(s_acc[nb][1], C1, mC2));
      float p2 = exp2x(fmaf(s_acc[nb][2], C1, mC2));
      float p3 = exp2x(fmaf(s_acc[nb][3], C1, mC2));
      int wr = (nb == 0) ? pswr0 : (nb == 1) ? pswr1 : (nb == 2) ? pswr2 : pswr3;
      *(uint2*)(myPs + wr) = make_uint2(pk2(p0, p1), pk2(p2, p3));
      l_i += (p0 + p1) + (p2 + p3);
    }

    bf16x8 af0 = *(const bf16x8*)(myPs + psrd0);
    bf16x8 af1 = *(const bf16x8*)(myPs + psrd1);
#pragma unroll
    for (int nb = 0; nb < 4; nb++) {
      o_acc[nb] = __builtin_amdgcn_mfma_f32_16x16x32_bf16(af0, vfr[nb][0], o_acc[nb], 0, 0, 0);
      o_acc[nb] = __builtin_amdgcn_mfma_f32_16x16x32_bf16(af1, vfr[nb][1], o_acc[nb], 0, 0, 0);
    }

    asm volatile("s_waitcnt vmcnt(0)" ::: "memory");
    __builtin_amdgcn_s_barrier();
    short* t;
    t = kcur; kcur = knxt; knxt = t;
    t = vcur; vcur = vnxt; vnxt = t;
  }

  // -------- peeled diagonal ktile (kt == qt), with causal mask --------
  {
    const int ql = wave * 16 + col;      // q row within the 64-row tile
    const int kl = quad * 4;             // key base within 16-chunk

    bf16x8 kfr[4][2], vfr[4][2];
#pragma unroll
    for (int nb = 0; nb < 4; nb++) {
      kfr[nb][0] = *(const bf16x8*)(kcur + (nb * 2 + 0) * 512 + lane * 8);
      kfr[nb][1] = *(const bf16x8*)(kcur + (nb * 2 + 1) * 512 + lane * 8);
      vfr[nb][0] = *(const bf16x8*)(vcur + (nb * 2 + 0) * 512 + lane * 8);
      vfr[nb][1] = *(const bf16x8*)(vcur + (nb * 2 + 1) * 512 + lane * 8);
    }

    f32x4 s_acc[4];
#pragma unroll
    for (int nb = 0; nb < 4; nb++) {
      f32x4 z = (f32x4){0.f, 0.f, 0.f, 0.f};
      z = __builtin_amdgcn_mfma_f32_16x16x32_bf16(kfr[nb][0], qf0, z, 0, 0, 0);
      z = __builtin_amdgcn_mfma_f32_16x16x32_bf16(kfr[nb][1], qf1, z, 0, 0, 0);
      s_acc[nb] = z;
    }

#pragma unroll
    for (int nb = 0; nb < 4; nb++) {
      float pv[4];
#pragma unroll
      for (int r = 0; r < 4; r++) {
        pv[r] = exp2x(fmaf(s_acc[nb][r], C1, mC2));
        if ((nb * 16 + kl + r) > ql) pv[r] = 0.f;
      }
      int wr = (nb == 0) ? pswr0 : (nb == 1) ? pswr1 : (nb == 2) ? pswr2 : pswr3;
      *(uint2*)(myPs + wr) = make_uint2(pk2(pv[0], pv[1]), pk2(pv[2], pv[3]));
      l_i += (pv[0] + pv[1]) + (pv[2] + pv[3]);
    }

    bf16x8 af0 = *(const bf16x8*)(myPs + psrd0);
    bf16x8 af1 = *(const bf16x8*)(myPs + psrd1);
#pragma unroll
    for (int nb = 0; nb < 4; nb++) {
      o_acc[nb] = __builtin_amdgcn_mfma_f32_16x16x32_bf16(af0, vfr[nb][0], o_acc[nb], 0, 0, 0);
      o_acc[nb] = __builtin_amdgcn_mfma_f32_16x16x32_bf16(af1, vfr[nb][1], o_acc[nb], 0, 0, 0);
    }
  }

  // l reduction over the 4 quads sharing this col
  l_i += __shfl_xor(l_i, 16);
  l_i += __shfl_xor(l_i, 32);
  float invl = 1.0f / l_i;

#pragma unroll
  for (int r = 0; r < 4; r++) {
    float inv = __shfl(invl, quad * 4 + r);   // lane whose col == quad*4+r
    size_t row = (size_t)(b * 2048 + qt * 64 + wave * 16 + quad * 4 + r);
#pragma unroll
    for (int nb = 0; nb < 4; nb++)
      ctx[row * 1024 + h * 64 + nb * 16 + col] = f2bf(o_acc[nb][r] * inv);
  }
}

// ---------------------------------------------------------------------------
extern "C" void kernel_launch(void* const* d_in, const int* in_sizes, int n_in,
                              void* d_out, int out_size, void* d_ws, size_t ws_size,
                              hipStream_t stream) {
  const float* X  = (const float*)d_in[0];
  const int* pos  = (const int*)d_in[1];
  const float* wq = (const float*)d_in[2];
  const float* wk = (const float*)d_in[3];
  const float* wv = (const float*)d_in[4];
  const float* wo = (const float*)d_in[5];
  float* out = (float*)d_out;

  short* Xb  = (short*)d_ws;
  short* Wqb = Xb + (1 << 22);
  short* Wkb = Wqb + (1 << 20);
  short* Wvb = Wkb + (1 << 20);
  short* Wob = Wvb + (1 << 20);
  short* Qb  = Wob + (1 << 20);
  short* Kfb = Qb + (1 << 22);
  short* Vfb = Kfb + (1 << 22);
  short* Ctx = Vfb + (1 << 22);

  cast_all<<<8192, 256, 0, stream>>>((const float4*)X, (const float4*)wq, (const float4*)wk,
                                     (const float4*)wv, (const float4*)wo, Xb, Wqb);
  qkv_gemm<<<dim3(32, 8, 3), 256, 0, stream>>>(Xb, Wqb, Wkb, Wvb, Qb, Kfb, Vfb, pos);
  flash_attn<<<dim3(32, 32), 256, 0, stream>>>(Qb, Kfb, Vfb, Ctx);
  out_gemm<<<dim3(64, 8), 256, 0, stream>>>(Ctx, Wob, out);
}

// Round 6
// 166.117 us; speedup vs baseline: 1.1062x; 1.0101x over previous
//
#include <hip/hip_runtime.h>

// ---------------------------------------------------------------------------
// Multihead self-attention with RoPE, MI355X (gfx950).  Round 15 (= R14 resub).
// B=2, S=2048, H=16, DH=64, DM=1024.
// R14 never ran (container infra failure x2); resubmitting with one defensive
// fix: zero-init the flash pipeline regs (afp/vfp) that were formally
// uninitialized on the qt==0 path.
// R14a (qkv): RoPE in-lane via d-permutation. Head dim permuted IDENTICALLY
// for Q and K (pos j<32 := orig 2j, j>=32 := orig 2j+1) by remapping Wq/Wk
// ROW ORDER at staging (global src perm, LDS linear). QK^T invariant under
// common d-perm; V/ctx/Wo untouched. RoPE pair now in-lane (acc[ni] vs
// acc[ni+2]): deletes 64 ds_bpermute + ~200 VALU per wave epilogue.
// R14b (flash): software-pipeline PV across ktiles: iter kt = QK(kt) +
// PV(kt-1) from reg-held P/V frags, then softmax(kt) -> exp/pack/LDS-bounce
// latency hides under the PV MFMA cluster. V frags read to regs after the
// PV consuming the old ones. s_setprio(1) around MFMA clusters.
// ---------------------------------------------------------------------------

typedef __attribute__((ext_vector_type(8))) short bf16x8;
typedef __attribute__((ext_vector_type(4))) float f32x4;

__device__ __forceinline__ short f2bf(float f) {
  unsigned u = __float_as_uint(f);
  unsigned r = (u + 0x7fffu + ((u >> 16) & 1u)) >> 16;   // RNE
  return (short)(r & 0xFFFFu);
}

// pack two f32 -> adjacent bf16 (round-half-up via +0x8000), one v_perm_b32
__device__ __forceinline__ unsigned pk2(float a, float b) {
  return __builtin_amdgcn_perm(__float_as_uint(b) + 0x8000u,
                               __float_as_uint(a) + 0x8000u, 0x07060302u);
}

// native 2^x, one v_exp_f32 (bypasses OCML guard sequence)
__device__ __forceinline__ float exp2x(float x) {
  float r;
  asm("v_exp_f32 %0, %1" : "=v"(r) : "v"(x));
  return r;
}

// async global->LDS, 16B per lane. LDS dest must be wave-uniform base + lane*16.
__device__ __forceinline__ void async16(const void* g, void* l) {
  __builtin_amdgcn_global_load_lds(
      (const __attribute__((address_space(1))) void*)g,
      (__attribute__((address_space(3))) void*)l, 16, 0, 0);
}

__device__ __forceinline__ void cstore(short* C, size_t i, float v) { C[i] = f2bf(v); }
__device__ __forceinline__ void cstore(float* C, size_t i, float v) { C[i] = v; }

// ---------------------------------------------------------------------------
// merged f32 -> bf16 cast: X (1M float4) then Wq|Wk|Wv|Wo (dsts contiguous).
// ---------------------------------------------------------------------------
__global__ void cast_all(const float4* __restrict__ X,
                         const float4* __restrict__ w0, const float4* __restrict__ w1,
                         const float4* __restrict__ w2, const float4* __restrict__ w3,
                         short* __restrict__ Xb, short* __restrict__ Wb) {
  int t = blockIdx.x * 256 + threadIdx.x;
  const float4* s;
  short4* d;
  if (t < (1 << 20)) {
    s = X + t; d = (short4*)Xb + t;
  } else {
    int u = t - (1 << 20);
    int which = u >> 18;
    s = ((which == 0) ? w0 : (which == 1) ? w1 : (which == 2) ? w2 : w3) + (u & 0x3FFFF);
    d = (short4*)Wb + u;
  }
  float4 v = *s;
  *d = make_short4(f2bf(v.x), f2bf(v.y), f2bf(v.z), f2bf(v.w));
}

// ---------------------------------------------------------------------------
// bf16 GEMM core: C[M,N] = A[M,K] * B[N,K]^T, K=1024, lda=ldb=1024.
// BM=32*MR, BN=32*NR; 4 waves 2x2. LDS passed in (3 buffers each for A,B).
// 3-deep ring, prefetch 2 K-tiles ahead, counted vmcnt + raw s_barrier.
// MAPB: permute B rows within each 64-block (j<32 -> 2j, j>=32 -> 2j+1) so
// RoPE pairs land in-lane (requires NR==4, head=64).
// ---------------------------------------------------------------------------
enum EpiMode { EPI_ROW, EPI_KFRAG, EPI_VFRAG };

template <typename OUT, int MR, int NR, bool ROPE, EpiMode EM, bool MAPB>
__device__ __forceinline__ void gemm_core(short* __restrict__ As, short* __restrict__ Bs,
                                          const short* __restrict__ A, const short* __restrict__ B,
                                          OUT* __restrict__ C, int bm, int bn, int ldc,
                                          const int* __restrict__ pos) {
  constexpr int BM = 32 * MR, BN = 32 * NR;
  constexpr int NLD = (BM * 4 + BN * 4) / 256;   // global_load_lds per wave per stage
  const int tid  = threadIdx.x;
  const int lane = tid & 63, wave = tid >> 6;
  const int col  = lane & 15, quad = lane >> 4;
  const int wm = (wave & 1) * (16 * MR), wn = (wave >> 1) * (16 * NR);

  f32x4 acc[MR][NR];
#pragma unroll
  for (int i = 0; i < MR; i++)
#pragma unroll
    for (int j = 0; j < NR; j++) acc[i][j] = (f32x4){0.f, 0.f, 0.f, 0.f};

  auto stage = [&](int k0, int bu) {
#pragma unroll
    for (int c = tid; c < BM * 4; c += 256) {
      int r = c >> 2, cc = (c & 3) << 3;
      async16(A + (size_t)(bm + r) * 1024 + k0 + cc, As + bu * BM * 32 + c * 8);
    }
#pragma unroll
    for (int c = tid; c < BN * 4; c += 256) {
      int r = c >> 2, cc = (c & 3) << 3;
      int rg = bn + r;
      if (MAPB) {
        int k6 = rg & 63;
        rg = (rg & ~63) | ((k6 < 32) ? (k6 << 1) : (((k6 - 32) << 1) | 1));
      }
      async16(B + (size_t)rg * 1024 + k0 + cc, Bs + bu * BN * 32 + c * 8);
    }
  };

  // prologue: 2 stages in flight, wait for stage 0 only (vmcnt leaves NLD).
  stage(0, 0);
  stage(32, 1);
  if constexpr (NLD == 4) asm volatile("s_waitcnt vmcnt(4)" ::: "memory");
  else                    asm volatile("s_waitcnt vmcnt(3)" ::: "memory");
  __builtin_amdgcn_s_barrier();

  int cur = 0, nxt = 2;
  for (int it = 0; it < 32; ++it) {
    if (it < 30) stage((it + 2) * 32, nxt);
    const short* as = As + cur * (BM * 32);
    const short* bs = Bs + cur * (BN * 32);

    bf16x8 af[MR], bfr[NR];
#pragma unroll
    for (int i = 0; i < MR; i++)
      af[i] = *(const bf16x8*)(as + (wm + i * 16 + col) * 32 + quad * 8);
#pragma unroll
    for (int i = 0; i < NR; i++)
      bfr[i] = *(const bf16x8*)(bs + (wn + i * 16 + col) * 32 + quad * 8);
#pragma unroll
    for (int mi = 0; mi < MR; mi++)
#pragma unroll
      for (int ni = 0; ni < NR; ni++)
        acc[mi][ni] = __builtin_amdgcn_mfma_f32_16x16x32_bf16(af[mi], bfr[ni], acc[mi][ni], 0, 0, 0);

    // counted drain: oldest stage (it+1) must have landed; newest (it+2) may fly.
    if (it < 30) {
      if constexpr (NLD == 4) asm volatile("s_waitcnt vmcnt(4)" ::: "memory");
      else                    asm volatile("s_waitcnt vmcnt(3)" ::: "memory");
    } else {
      asm volatile("s_waitcnt vmcnt(0)" ::: "memory");
    }
    __builtin_amdgcn_s_barrier();
    cur = (cur == 2) ? 0 : cur + 1;
    nxt = (nxt == 2) ? 0 : nxt + 1;
  }

  if (ROPE) {
    // d-permuted layout: within each head, position j<32 = x of pair j,
    // j>=32 = y of pair j. Pair (j, j+32) = (acc[ni], acc[ni+2]), same lane.
    float invf[2];
#pragma unroll
    for (int ni = 0; ni < 2; ni++) {
      int p = ni * 16 + col;                 // pair index within head (0..31)
      invf[ni] = exp2f(-0.4152410118609203f * (float)p) * 0.15915494309189535f;
    }
#pragma unroll
    for (int mi = 0; mi < MR; mi++) {
#pragma unroll
      for (int r = 0; r < 4; r++) {
        int row = bm + wm + mi * 16 + quad * 4 + r;
        float fp = (float)pos[row & 2047];
#pragma unroll
        for (int ni = 0; ni < 2; ni++) {
          float rev = fp * invf[ni];
          rev -= floorf(rev);
          float sn = __builtin_amdgcn_sinf(rev);
          float cs = __builtin_amdgcn_cosf(rev);
          float x  = acc[mi][ni][r];
          float yv = acc[mi][ni + 2][r];
          acc[mi][ni][r]     = fmaf(x, cs, -yv * sn);
          acc[mi][ni + 2][r] = fmaf(yv, cs, x * sn);
        }
      }
    }
  }

  if (EM == EPI_ROW) {
#pragma unroll
    for (int mi = 0; mi < MR; mi++) {
#pragma unroll
      for (int r = 0; r < 4; r++) {
        size_t row = (size_t)(bm + wm + mi * 16 + quad * 4 + r);
#pragma unroll
        for (int ni = 0; ni < NR; ni++) {
          int cg = bn + wn + ni * 16 + col;
          cstore(C, row * ldc + cg, acc[mi][ni][r]);
        }
      }
    }
  } else if (EM == EPI_KFRAG) {
    // rows m = tokens, cols e = embed
#pragma unroll
    for (int mi = 0; mi < MR; mi++) {
#pragma unroll
      for (int r = 0; r < 4; r++) {
        int m = bm + wm + mi * 16 + quad * 4 + r;
        int bq = m >> 11, key = m & 2047;
        int kt = key >> 6, nb = (key >> 4) & 3, cl = key & 15;
#pragma unroll
        for (int ni = 0; ni < NR; ni++) {
          int e = bn + wn + ni * 16 + col;
          int h = e >> 6, d = e & 63;
          size_t seg = ((((size_t)(bq * 16 + h) * 32 + kt) * 4 + nb) * 2 + (d >> 5));
          cstore((short*)C, seg * 512 + (((d >> 3) & 3) * 16 + cl) * 8 + (d & 7), acc[mi][ni][r]);
        }
      }
    }
  } else {   // EPI_VFRAG: rows e = embed, cols m = tokens
#pragma unroll
    for (int mi = 0; mi < MR; mi++) {
#pragma unroll
      for (int r = 0; r < 4; r++) {
        int e = bm + wm + mi * 16 + quad * 4 + r;
        int h = e >> 6, d = e & 63;
        int nb = d >> 4, cl = d & 15;
#pragma unroll
        for (int ni = 0; ni < NR; ni++) {
          int m = bn + wn + ni * 16 + col;
          int bq = m >> 11, key = m & 2047;
          int kt = key >> 6, k64 = key & 63;
          size_t seg = ((((size_t)(bq * 16 + h) * 32 + kt) * 4 + nb) * 2 + (k64 >> 5));
          cstore((short*)C, seg * 512 + (((k64 >> 3) & 3) * 16 + cl) * 8 + (k64 & 7), acc[mi][ni][r]);
        }
      }
    }
  }
}

// z=0: Q = rope(X Wq^T) row-major (d-permuted); z=1: Kf = rope(X Wk^T)
// frag-major (d-permuted); z=2: Vf = Wv X^T frag-major (not permuted).
__global__ __launch_bounds__(256, 3) void qkv_gemm(const short* __restrict__ Xb,
                                                   const short* __restrict__ Wq,
                                                   const short* __restrict__ Wk,
                                                   const short* __restrict__ Wv,
                                                   short* __restrict__ Qo,
                                                   short* __restrict__ Kf,
                                                   short* __restrict__ Vf,
                                                   const int* __restrict__ pos) {
  __shared__ __align__(16) short sm[3 * 128 * 32 + 3 * 128 * 32];   // 48 KB shared
  short* As = sm;
  short* Bs = sm + 3 * 128 * 32;
  const int z = blockIdx.z;
  if (z == 0)      gemm_core<short, 4, 4, true,  EPI_ROW,   true >(As, Bs, Xb, Wq, Qo, blockIdx.x * 128, blockIdx.y * 128, 1024, pos);
  else if (z == 1) gemm_core<short, 4, 4, true,  EPI_KFRAG, true >(As, Bs, Xb, Wk, Kf, blockIdx.x * 128, blockIdx.y * 128, 0, pos);
  else             gemm_core<short, 4, 4, false, EPI_VFRAG, false>(As, Bs, Wv, Xb, Vf, blockIdx.y * 128, blockIdx.x * 128, 0, pos);
}

__global__ __launch_bounds__(256) void out_gemm(const short* __restrict__ Ctx,
                                                const short* __restrict__ Wo,
                                                float* __restrict__ C) {
  __shared__ __align__(16) short sm[3 * 64 * 32 + 3 * 128 * 32];    // 36 KB
  gemm_core<float, 2, 4, false, EPI_ROW, false>(sm, sm + 3 * 64 * 32, Ctx, Wo, C,
                                                blockIdx.x * 64, blockIdx.y * 128, 1024, nullptr);
}

// ---------------------------------------------------------------------------
// Flash attention, causal. grid (bh=32, y=32), 256 threads = 4 waves, each
// wave = one 16-row strip of the block's 64-row qtile. K/V LDS-staged,
// double-buffered, vmcnt(0)+s_barrier per ktile. Software-pipelined:
// iter kt: QK(kt) + PV(kt-1) [reg-held P/V frags], then softmax(kt); V(kt)
// read to regs after PV consumed V(kt-1). Diag ktile peeled with mask +
// final PV. setprio(1) around MFMA clusters. LPT qt permutation, 3 blk/CU.
// ---------------------------------------------------------------------------
__global__ __launch_bounds__(256, 3) void flash_attn(const short* __restrict__ Q,
                                                     const short* __restrict__ Kf,
                                                     const short* __restrict__ Vf,
                                                     short* __restrict__ ctx) {
  const int y = blockIdx.y;
  const int g = y >> 3, r8 = y & 7;
  const int qt = (g == 0) ? 31 - r8 : (g == 1) ? r8 : (g == 2) ? 23 - r8 : 8 + r8;
  const int bh = blockIdx.x;
  const int b = bh >> 4, h = bh & 15;
  __shared__ __align__(16) short Ps[4][16 * 72];         // per-wave P [q][key-chunk^]
  __shared__ __align__(16) short Ksm[2][4096];           // 8 KB per buffer
  __shared__ __align__(16) short Vsm[2][4096];
  const int tid = threadIdx.x, lane = tid & 63, wave = tid >> 6;
  const int col = lane & 15, quad = lane >> 4;

  const short* Kg = Kf + (size_t)bh * 131072;
  const short* Vg = Vf + (size_t)bh * 131072;

  const float C1 = 0.18033688011112042f;    // 0.125 * log2(e)
  const float mC2 = -17.31234049066756f;    // -12 * log2(e)

  short* myPs = &Ps[wave][0];
  const int cx = col & 3;
  const int pswr0 = col * 72 + ((0 ^ cx) << 4) + quad * 4;
  const int pswr1 = col * 72 + ((1 ^ cx) << 4) + quad * 4;
  const int pswr2 = col * 72 + ((2 ^ cx) << 4) + quad * 4;
  const int pswr3 = col * 72 + ((3 ^ cx) << 4) + quad * 4;
  const int psrd0 = col * 72 + (((quad >> 1) ^ cx) << 4) + (quad & 1) * 8;
  const int psrd1 = col * 72 + ((((quad >> 1) + 2) ^ cx) << 4) + (quad & 1) * 8;

  auto stageKV = [&](int kt, short* kb, short* vb) {
    const short* kg = Kg + kt * 4096;
    const short* vg = Vg + kt * 4096;
#pragma unroll
    for (int c = tid; c < 512; c += 256) {
      async16(kg + c * 8, kb + c * 8);
      async16(vg + c * 8, vb + c * 8);
    }
  };

  // Q fragments (B-operand), one-time row-major gather
  const size_t qrow = (size_t)(b * 2048 + qt * 64 + wave * 16 + col);
  bf16x8 qf0 = *(const bf16x8*)(Q + qrow * 1024 + h * 64 + quad * 8);
  bf16x8 qf1 = *(const bf16x8*)(Q + qrow * 1024 + h * 64 + 32 + quad * 8);

  float l_i = 0.f;                                     // one q per lane (q=col)
  f32x4 o_acc[4];
#pragma unroll
  for (int i = 0; i < 4; i++) o_acc[i] = (f32x4){0.f, 0.f, 0.f, 0.f};

  short *kcur = &Ksm[0][0], *vcur = &Vsm[0][0];
  short *knxt = &Ksm[1][0], *vnxt = &Vsm[1][0];

  stageKV(0, kcur, vcur);
  asm volatile("s_waitcnt vmcnt(0)" ::: "memory");
  __builtin_amdgcn_s_barrier();

  // pipeline state: P frags + V frags of the previous ktile (registers)
  bf16x8 afp0 = (bf16x8){0,0,0,0,0,0,0,0}, afp1 = (bf16x8){0,0,0,0,0,0,0,0};
  bf16x8 vfp[4][2];
#pragma unroll
  for (int i = 0; i < 4; i++) vfp[i][0] = vfp[i][1] = (bf16x8){0,0,0,0,0,0,0,0};

  // -------- main loop (maskless; diag peeled). iter kt: QK(kt) + PV(kt-1) --
  for (int kt = 0; kt < qt; ++kt) {
    stageKV(kt + 1, knxt, vnxt);

    bf16x8 kfr[4][2];
#pragma unroll
    for (int nb = 0; nb < 4; nb++) {
      kfr[nb][0] = *(const bf16x8*)(kcur + (nb * 2 + 0) * 512 + lane * 8);
      kfr[nb][1] = *(const bf16x8*)(kcur + (nb * 2 + 1) * 512 + lane * 8);
    }

    f32x4 s_acc[4];
    __builtin_amdgcn_s_setprio(1);
#pragma unroll
    for (int nb = 0; nb < 4; nb++) {
      f32x4 z = (f32x4){0.f, 0.f, 0.f, 0.f};
      z = __builtin_amdgcn_mfma_f32_16x16x32_bf16(kfr[nb][0], qf0, z, 0, 0, 0);
      z = __builtin_amdgcn_mfma_f32_16x16x32_bf16(kfr[nb][1], qf1, z, 0, 0, 0);
      s_acc[nb] = z;
    }
    if (kt > 0) {   // PV of previous tile, independent of s_acc -> overlaps exp
#pragma unroll
      for (int nb = 0; nb < 4; nb++) {
        o_acc[nb] = __builtin_amdgcn_mfma_f32_16x16x32_bf16(afp0, vfp[nb][0], o_acc[nb], 0, 0, 0);
        o_acc[nb] = __builtin_amdgcn_mfma_f32_16x16x32_bf16(afp1, vfp[nb][1], o_acc[nb], 0, 0, 0);
      }
    }
    __builtin_amdgcn_s_setprio(0);

    // V(kt) into regs (old vfp just consumed above)
#pragma unroll
    for (int nb = 0; nb < 4; nb++) {
      vfp[nb][0] = *(const bf16x8*)(vcur + (nb * 2 + 0) * 512 + lane * 8);
      vfp[nb][1] = *(const bf16x8*)(vcur + (nb * 2 + 1) * 512 + lane * 8);
    }

    // softmax(kt) -> Ps -> afp
#pragma unroll
    for (int nb = 0; nb < 4; nb++) {
      float p0 = exp2x(fmaf(s_acc[nb][0], C1, mC2));
      float p1 = exp2x(fmaf(s_acc[nb][1], C1, mC2));
      float p2 = exp2x(fmaf(s_acc[nb][2], C1, mC2));
      float p3 = exp2x(fmaf(s_acc[nb][3], C1, mC2));
      int wr = (nb == 0) ? pswr0 : (nb == 1) ? pswr1 : (nb == 2) ? pswr2 : pswr3;
      *(uint2*)(myPs + wr) = make_uint2(pk2(p0, p1), pk2(p2, p3));
      l_i += (p0 + p1) + (p2 + p3);
    }
    afp0 = *(const bf16x8*)(myPs + psrd0);
    afp1 = *(const bf16x8*)(myPs + psrd1);

    asm volatile("s_waitcnt vmcnt(0)" ::: "memory");
    __builtin_amdgcn_s_barrier();
    short* t;
    t = kcur; kcur = knxt; knxt = t;
    t = vcur; vcur = vnxt; vnxt = t;
  }

  // -------- peeled diagonal ktile (kt == qt): mask + drain pipeline --------
  {
    const int ql = wave * 16 + col;
    const int kl = quad * 4;

    bf16x8 kfr[4][2];
#pragma unroll
    for (int nb = 0; nb < 4; nb++) {
      kfr[nb][0] = *(const bf16x8*)(kcur + (nb * 2 + 0) * 512 + lane * 8);
      kfr[nb][1] = *(const bf16x8*)(kcur + (nb * 2 + 1) * 512 + lane * 8);
    }

    f32x4 s_acc[4];
    __builtin_amdgcn_s_setprio(1);
#pragma unroll
    for (int nb = 0; nb < 4; nb++) {
      f32x4 z = (f32x4){0.f, 0.f, 0.f, 0.f};
      z = __builtin_amdgcn_mfma_f32_16x16x32_bf16(kfr[nb][0], qf0, z, 0, 0, 0);
      z = __builtin_amdgcn_mfma_f32_16x16x32_bf16(kfr[nb][1], qf1, z, 0, 0, 0);
      s_acc[nb] = z;
    }
    if (qt > 0) {   // PV of tile qt-1
#pragma unroll
      for (int nb = 0; nb < 4; nb++) {
        o_acc[nb] = __builtin_amdgcn_mfma_f32_16x16x32_bf16(afp0, vfp[nb][0], o_acc[nb], 0, 0, 0);
        o_acc[nb] = __builtin_amdgcn_mfma_f32_16x16x32_bf16(afp1, vfp[nb][1], o_acc[nb], 0, 0, 0);
      }
    }
    __builtin_amdgcn_s_setprio(0);

#pragma unroll
    for (int nb = 0; nb < 4; nb++) {
      vfp[nb][0] = *(const bf16x8*)(vcur + (nb * 2 + 0) * 512 + lane * 8);
      vfp[nb][1] = *(const bf16x8*)(vcur + (nb * 2 + 1) * 512 + lane * 8);
    }

#pragma unroll
    for (int nb = 0; nb < 4; nb++) {
      float pv[4];
#pragma unroll
      for (int r = 0; r < 4; r++) {
        pv[r] = exp2x(fmaf(s_acc[nb][r], C1, mC2));
        if ((nb * 16 + kl + r) > ql) pv[r] = 0.f;
      }
      int wr = (nb == 0) ? pswr0 : (nb == 1) ? pswr1 : (nb == 2) ? pswr2 : pswr3;
      *(uint2*)(myPs + wr) = make_uint2(pk2(pv[0], pv[1]), pk2(pv[2], pv[3]));
      l_i += (pv[0] + pv[1]) + (pv[2] + pv[3]);
    }
    afp0 = *(const bf16x8*)(myPs + psrd0);
    afp1 = *(const bf16x8*)(myPs + psrd1);

    __builtin_amdgcn_s_setprio(1);
#pragma unroll
    for (int nb = 0; nb < 4; nb++) {
      o_acc[nb] = __builtin_amdgcn_mfma_f32_16x16x32_bf16(afp0, vfp[nb][0], o_acc[nb], 0, 0, 0);
      o_acc[nb] = __builtin_amdgcn_mfma_f32_16x16x32_bf16(afp1, vfp[nb][1], o_acc[nb], 0, 0, 0);
    }
    __builtin_amdgcn_s_setprio(0);
  }

  // l reduction over the 4 quads sharing this col
  l_i += __shfl_xor(l_i, 16);
  l_i += __shfl_xor(l_i, 32);
  float invl = 1.0f / l_i;

#pragma unroll
  for (int r = 0; r < 4; r++) {
    float inv = __shfl(invl, quad * 4 + r);   // lane whose col == quad*4+r
    size_t row = (size_t)(b * 2048 + qt * 64 + wave * 16 + quad * 4 + r);
#pragma unroll
    for (int nb = 0; nb < 4; nb++)
      ctx[row * 1024 + h * 64 + nb * 16 + col] = f2bf(o_acc[nb][r] * inv);
  }
}

// ---------------------------------------------------------------------------
extern "C" void kernel_launch(void* const* d_in, const int* in_sizes, int n_in,
                              void* d_out, int out_size, void* d_ws, size_t ws_size,
                              hipStream_t stream) {
  const float* X  = (const float*)d_in[0];
  const int* pos  = (const int*)d_in[1];
  const float* wq = (const float*)d_in[2];
  const float* wk = (const float*)d_in[3];
  const float* wv = (const float*)d_in[4];
  const float* wo = (const float*)d_in[5];
  float* out = (float*)d_out;

  short* Xb  = (short*)d_ws;
  short* Wqb = Xb + (1 << 22);
  short* Wkb = Wqb + (1 << 20);
  short* Wvb = Wkb + (1 << 20);
  short* Wob = Wvb + (1 << 20);
  short* Qb  = Wob + (1 << 20);
  short* Kfb = Qb + (1 << 22);
  short* Vfb = Kfb + (1 << 22);
  short* Ctx = Vfb + (1 << 22);

  cast_all<<<8192, 256, 0, stream>>>((const float4*)X, (const float4*)wq, (const float4*)wk,
                                     (const float4*)wv, (const float4*)wo, Xb, Wqb);
  qkv_gemm<<<dim3(32, 8, 3), 256, 0, stream>>>(Xb, Wqb, Wkb, Wvb, Qb, Kfb, Vfb, pos);
  flash_attn<<<dim3(32, 32), 256, 0, stream>>>(Qb, Kfb, Vfb, Ctx);
  out_gemm<<<dim3(64, 8), 256, 0, stream>>>(Ctx, Wob, out);
}